// Round 4
// baseline (2556.304 us; speedup 1.0000x reference)
//
#include <hip/hip_runtime.h>

typedef __bf16 v8bf __attribute__((ext_vector_type(8)));
typedef float v4f __attribute__((ext_vector_type(4)));
typedef unsigned short u16;
typedef unsigned int u32;

#define DEVI __device__ __forceinline__

constexpr int LX = 168, FF = 64;
constexpr int LY = 72, FT = 22, FOUTC = 10;
constexpr int HID = 256;
constexpr int HSTR = 264;   // u16/row for h tiles (528B = 33*16, 16B-aligned rows)
constexpr int UST2 = 40;    // u16/row for decoder input tiles (80B)
constexpr int A1STR = 264;  // u16/row for a1

// bf16 weight cache layout in d_ws (u16 element offsets; all 16B-aligned)
constexpr int W_EWIH = 0;                      // 768*64
constexpr int W_EWHH = 49152;                  // 768*256
constexpr int W_DWIH = 245760;                 // 768*32
constexpr int W_DWHH = 270336;                 // 768*256
constexpr int W_THW0 = 466944;                 // 128*256
constexpr int W_THW1 = 499712;                 // 2*128
constexpr int W_CLW0 = 499968;                 // 128*256
constexpr int W_CLW1 = 532736;                 // 8*128
constexpr int W_TOTAL = 533760;                // ~1.04 MB as u16

DEVI u16 f2bf(float f) {
  u32 x; __builtin_memcpy(&x, &f, 4);
  return (u16)((x + 0x7FFFu + ((x >> 16) & 1u)) >> 16);  // RNE
}
DEVI float sigm(float x) { return 1.f / (1.f + __expf(-x)); }
DEVI float tanh_(float x) {
  float e = __expf(-2.f * fabsf(x));
  return copysignf((1.f - e) / (1.f + e), x);
}
DEVI float smelu_(float x) {
  if (x >= 1.1f) return x;
  if (x <= -1.1f) return 0.f;
  float u = x + 1.1f;
  return u * u * (1.f / 4.4f);
}
DEVI v8bf ld8(const u16* p) { return *reinterpret_cast<const v8bf*>(p); }
DEVI v4f mfma16(v8bf a, v8bf b, v4f c) {
  return __builtin_amdgcn_mfma_f32_16x16x32_bf16(a, b, c, 0, 0, 0);
}
DEVI v8bf cvtf4(float4 lo, float4 hi) {
  v8bf r;
  r[0] = (__bf16)lo.x; r[1] = (__bf16)lo.y; r[2] = (__bf16)lo.z; r[3] = (__bf16)lo.w;
  r[4] = (__bf16)hi.x; r[5] = (__bf16)hi.y; r[6] = (__bf16)hi.z; r[7] = (__bf16)hi.w;
  return r;
}

// ---- prologue: convert all weight matrices f32 -> bf16 into d_ws ----
__global__ void cvt_weights(const float* __restrict__ eWih, const float* __restrict__ eWhh,
                            const float* __restrict__ dWih, const float* __restrict__ dWhh,
                            const float* __restrict__ thW0, const float* __restrict__ thW1,
                            const float* __restrict__ clW0, const float* __restrict__ clW1,
                            u16* __restrict__ ws) {
  const int i = blockIdx.x * 256 + threadIdx.x;
  if (i >= W_TOTAL) return;
  const float* src; int off;
  if      (i < W_EWHH) { src = eWih; off = W_EWIH; }
  else if (i < W_DWIH) { src = eWhh; off = W_EWHH; }
  else if (i < W_DWHH) { src = dWih; off = W_DWIH; }
  else if (i < W_THW0) { src = dWhh; off = W_DWHH; }
  else if (i < W_THW1) { src = thW0; off = W_THW0; }
  else if (i < W_CLW0) { src = thW1; off = W_THW1; }
  else if (i < W_CLW1) { src = clW0; off = W_CLW0; }
  else                 { src = clW1; off = W_CLW1; }
  ws[i] = f2bf(src[i - off]);
}

template <int NKI>
DEVI void load_tile(v8bf (&wb)[NKI + 8], const u16* __restrict__ Wih,
                    const u16* __restrict__ Whh, int m, int quad) {
  const u16* pih = Wih + (size_t)m * (NKI * 32) + quad * 8;
  const u16* phh = Whh + (size_t)m * HID + quad * 8;
#pragma unroll
  for (int kt = 0; kt < NKI; ++kt) wb[kt] = ld8(pih + kt * 32);
#pragma unroll
  for (int kt = 0; kt < 8; ++kt) wb[NKI + kt] = ld8(phh + kt * 32);
}

// One GRU step, software-pipelined over the 6 gate tiles: tile i+1's 10 weight
// fragments load while tile i's MFMAs run (double-buffered in VGPRs), so
// 10-20 loads stay in flight instead of 1-2 (round-3 kernel was latency-bound
// on serialized B-fragment loads: 24K cyc/step at ~300 cyc L2 latency each).
template <int NKI>
DEVI void gru_step(const v8bf* a, const u16* __restrict__ Wih,
                   const u16* __restrict__ Whh,
                   const float (&bi)[6], const float (&bh)[6],
                   float (&hreg)[2][4], int wave, int col16, int quad) {
  v8bf wb[2][NKI + 8];
  float sr[2][4], sz[2][4], pi[2][4], ph[2][4];
  load_tile<NKI>(wb[0], Wih, Whh, wave * 16 + col16, quad);
#pragma unroll
  for (int i = 0; i < 6; ++i) {
    if (i < 5)
      load_tile<NKI>(wb[(i + 1) & 1], Wih, Whh, (wave + 8 * (i + 1)) * 16 + col16, quad);
    v4f ai = {0.f, 0.f, 0.f, 0.f};
    v4f ah = {0.f, 0.f, 0.f, 0.f};
#pragma unroll
    for (int kt = 0; kt < NKI; ++kt) ai = mfma16(a[kt], wb[i & 1][kt], ai);
#pragma unroll
    for (int kt = 0; kt < 8; ++kt) ah = mfma16(a[NKI + kt], wb[i & 1][NKI + kt], ah);
#pragma unroll
    for (int r = 0; r < 4; ++r) {
      const float vi = ai[r] + bi[i];
      const float vh = ah[r] + bh[i];
      if (i < 2)      sr[i][r] = vi + vh;
      else if (i < 4) sz[i - 2][r] = vi + vh;
      else { pi[i - 4][r] = vi; ph[i - 4][r] = vh; }
    }
  }
#pragma unroll
  for (int j = 0; j < 2; ++j)
#pragma unroll
    for (int r = 0; r < 4; ++r) {
      const float rg = sigm(sr[j][r]);
      const float zg = sigm(sz[j][r]);
      const float ng = tanh_(pi[j][r] + rg * ph[j][r]);
      hreg[j][r] = (1.f - zg) * ng + zg * hreg[j][r];
    }
}

__global__ __launch_bounds__(512, 2) void encdec_kernel(
    const float* __restrict__ xf, const float* __restrict__ yt, const float* __restrict__ pp,
    const float* __restrict__ ebih, const float* __restrict__ ebhh,
    const float* __restrict__ dbih, const float* __restrict__ dbhh,
    const float* __restrict__ thb0, const float* __restrict__ thb1,
    const float* __restrict__ clb0, const float* __restrict__ clb1,
    const u16* __restrict__ ws, float* __restrict__ outp) {
  __shared__ __align__(16) u16 hls[2][16 * HSTR];   // double-buffered h (bf16)
  __shared__ __align__(16) u16 uls[2][16 * UST2];   // double-buffered dec input
  __shared__ __align__(16) u16 a1buf[16 * A1STR];

  const u16* eWih = ws + W_EWIH;
  const u16* eWhh = ws + W_EWHH;
  const u16* dWih = ws + W_DWIH;
  const u16* dWhh = ws + W_DWHH;
  const u16* thW0 = ws + W_THW0;
  const u16* thW1 = ws + W_THW1;
  const u16* clW0 = ws + W_CLW0;
  const u16* clW1 = ws + W_CLW1;

  const int tid = threadIdx.x;
  const int wave = tid >> 6;
  const int lane = tid & 63;
  const int col16 = lane & 15;
  const int quad = lane >> 4;
  const int n0 = blockIdx.x * 16;

  for (int idx = tid; idx < 16 * HSTR; idx += 512) hls[0][idx] = 0;

  float hreg[2][4];
#pragma unroll
  for (int j = 0; j < 2; ++j)
#pragma unroll
    for (int r = 0; r < 4; ++r) hreg[j][r] = 0.f;

  float bi[6], bh[6];
#pragma unroll
  for (int i = 0; i < 6; ++i) {
    const int m = (wave + 8 * i) * 16 + col16;
    bi[i] = ebih[m];
    bh[i] = ebhh[m];
  }

  // x address base for this lane's A-row (batch row = col16): x[n][t][k]
  const float* xbase = xf + (size_t)(n0 + col16) * LX * FF + quad * 8;
  float4 xr0, xr1, xr2, xr3;  // raw f32 x for current step (prefetched)
  xr0 = *(const float4*)(xbase + 0);
  xr1 = *(const float4*)(xbase + 4);
  xr2 = *(const float4*)(xbase + 32);
  xr3 = *(const float4*)(xbase + 36);
  __syncthreads();  // h zero-init visible

  // ---------------- encoder: 168 steps, 1 barrier/step ----------------
#pragma unroll 1
  for (int t = 0; t < LX; ++t) {
    float4 xn0, xn1, xn2, xn3;
    if (t + 1 < LX) {  // prefetch next step's x across this step's compute
      const float* xn = xbase + (size_t)(t + 1) * FF;
      xn0 = *(const float4*)(xn + 0);
      xn1 = *(const float4*)(xn + 4);
      xn2 = *(const float4*)(xn + 32);
      xn3 = *(const float4*)(xn + 36);
    }
    v8bf a[10];
    a[0] = cvtf4(xr0, xr1);
    a[1] = cvtf4(xr2, xr3);
    const u16* hb = hls[t & 1] + col16 * HSTR + quad * 8;
#pragma unroll
    for (int kt = 0; kt < 8; ++kt) a[2 + kt] = ld8(hb + kt * 32);
    gru_step<2>(a, eWih, eWhh, bi, bh, hreg, wave, col16, quad);
#pragma unroll
    for (int j = 0; j < 2; ++j) {
      const int cidx = (wave + 8 * j) * 16 + col16;
#pragma unroll
      for (int r = 0; r < 4; ++r)
        hls[(t + 1) & 1][(quad * 4 + r) * HSTR + cidx] = f2bf(hreg[j][r]);
    }
    __syncthreads();  // h_t visible; prior reads of target region were 1 step ago
    xr0 = xn0; xr1 = xn1; xr2 = xn2; xr3 = xn3;
  }
  // h_enc now in hls[LX & 1] == hls[0]

  // ---------------- decoder setup ----------------
#pragma unroll
  for (int i = 0; i < 6; ++i) {
    const int m = (wave + 8 * i) * 16 + col16;
    bi[i] = dbih[m];
    bh[i] = dbhh[m];
  }
  float hb0[2];
#pragma unroll
  for (int i = 0; i < 2; ++i) {
    const int ct = wave + 8 * i;
    const int ml = (ct & 7) * 16 + col16;
    hb0[i] = (ct < 8) ? thb0[ml] : clb0[ml];
  }
  const bool w1th = (col16 < 2);
  const bool w1cl = (col16 >= 2 && col16 < FOUTC);
  const float b1v = w1th ? thb1[col16] : (w1cl ? clb1[col16 - 2] : 0.f);
  // hoist constant GEMM2 B fragments (block-diag thW1 (+) clW1) out of the loop
  v8bf w1f[8];
#pragma unroll
  for (int kt = 0; kt < 8; ++kt) {
    v8bf b;
#pragma unroll
    for (int j = 0; j < 8; ++j) b[j] = (__bf16)0.0f;
    if (kt < 4) {
      if (w1th) b = ld8(thW1 + col16 * 128 + kt * 32 + quad * 8);
    } else {
      if (w1cl) b = ld8(clW1 + (col16 - 2) * 128 + (kt - 4) * 32 + quad * 8);
    }
    w1f[kt] = b;
  }
  // decoder staging geometry: thread -> (row rr, col cc) of the 16x32 u tile
  const int srr = tid >> 5, scc = tid & 31;
  const size_t ybase = (size_t)(n0 + srr) * (LY + 1);
  // stage u_0 (src_t = 0)
  {
    float v = (scc < FT) ? yt[ybase * FT + scc] : pp[ybase * FOUTC + (scc - FT)];
    uls[0][srr * UST2 + scc] = f2bf(v);
  }
  __syncthreads();

  // ---------------- decoder: 72 steps, 2 barriers/step ----------------
#pragma unroll 1
  for (int t = 0; t < LY; ++t) {
    float unext = 0.f;
    if (t + 1 < LY) {  // prefetch staging value for u_{t+1} (src_t = t)
      unext = (scc < FT) ? yt[(ybase + t) * FT + scc]
                         : pp[(ybase + t) * FOUTC + (scc - FT)];
    }
    v8bf a[9];
    a[0] = ld8(uls[t & 1] + col16 * UST2 + quad * 8);
    const u16* hb = hls[t & 1] + col16 * HSTR + quad * 8;
#pragma unroll
    for (int kt = 0; kt < 8; ++kt) a[1 + kt] = ld8(hb + kt * 32);
    gru_step<1>(a, dWih, dWhh, bi, bh, hreg, wave, col16, quad);
#pragma unroll
    for (int j = 0; j < 2; ++j) {
      const int cidx = (wave + 8 * j) * 16 + col16;
#pragma unroll
      for (int r = 0; r < 4; ++r)
        hls[(t + 1) & 1][(quad * 4 + r) * HSTR + cidx] = f2bf(hreg[j][r]);
    }
    if (t + 1 < LY) uls[(t + 1) & 1][srr * UST2 + scc] = f2bf(unext);
    __syncthreads();  // Ba: h2 + u_{t+1} visible

    // head GEMM1: a1 = smelu(h2 @ W0^T + b0); all 16 B-fragment loads issued
    // before the MFMAs (two tiles/wave)
    {
      v8bf w0b[2][8];
#pragma unroll
      for (int i = 0; i < 2; ++i) {
        const int ct = wave + 8 * i;
        const u16* W0 = (ct < 8) ? thW0 : clW0;
        const u16* pw = W0 + (size_t)((ct & 7) * 16 + col16) * HID + quad * 8;
#pragma unroll
        for (int kt = 0; kt < 8; ++kt) w0b[i][kt] = ld8(pw + kt * 32);
      }
      v8bf ah2[8];
      const u16* h2b = hls[(t + 1) & 1] + col16 * HSTR + quad * 8;
#pragma unroll
      for (int kt = 0; kt < 8; ++kt) ah2[kt] = ld8(h2b + kt * 32);
#pragma unroll
      for (int i = 0; i < 2; ++i) {
        v4f acc = {0.f, 0.f, 0.f, 0.f};
#pragma unroll
        for (int kt = 0; kt < 8; ++kt) acc = mfma16(ah2[kt], w0b[i][kt], acc);
        const int ct = wave + 8 * i;
#pragma unroll
        for (int r = 0; r < 4; ++r)
          a1buf[(quad * 4 + r) * A1STR + ct * 16 + col16] =
              f2bf(smelu_(acc[r] + hb0[i]));
      }
    }
    __syncthreads();  // Bb: a1 visible

    // head GEMM2 (wave 0): one K=256 pass with pre-hoisted block-diag B
    if (wave == 0) {
      const u16* arow = a1buf + col16 * A1STR + quad * 8;
      v4f acc = {0.f, 0.f, 0.f, 0.f};
#pragma unroll
      for (int kt = 0; kt < 8; ++kt)
        acc = mfma16(ld8(arow + kt * 32), w1f[kt], acc);
      if (col16 < FOUTC) {
#pragma unroll
        for (int r = 0; r < 4; ++r)
          outp[((size_t)(n0 + quad * 4 + r) * LY + t) * FOUTC + col16] =
              acc[r] + b1v;
      }
    }
    // wave0's a1 reads are protected: next a1 write happens after Ba(t+1),
    // which wave0 reaches only after finishing GEMM2(t).
  }
}

extern "C" void kernel_launch(void* const* d_in, const int* in_sizes, int n_in,
                              void* d_out, int out_size, void* d_ws, size_t ws_size,
                              hipStream_t stream) {
  (void)in_sizes; (void)n_in; (void)ws_size; (void)out_size;
  const float* xf   = (const float*)d_in[0];
  // d_in[1] = x : unused by forward
  const float* yt   = (const float*)d_in[2];
  const float* pp   = (const float*)d_in[3];
  const float* eWih = (const float*)d_in[4];
  const float* eWhh = (const float*)d_in[5];
  const float* ebih = (const float*)d_in[6];
  const float* ebhh = (const float*)d_in[7];
  const float* dWih = (const float*)d_in[8];
  const float* dWhh = (const float*)d_in[9];
  const float* dbih = (const float*)d_in[10];
  const float* dbhh = (const float*)d_in[11];
  const float* thW0 = (const float*)d_in[12];
  const float* thb0 = (const float*)d_in[13];
  const float* thW1 = (const float*)d_in[14];
  const float* thb1 = (const float*)d_in[15];
  const float* clW0 = (const float*)d_in[16];
  const float* clb0 = (const float*)d_in[17];
  const float* clW1 = (const float*)d_in[18];
  const float* clb1 = (const float*)d_in[19];
  float* outp = (float*)d_out;
  u16* ws = (u16*)d_ws;  // needs W_TOTAL*2 ~= 1.04 MB of scratch

  cvt_weights<<<dim3((W_TOTAL + 255) / 256), dim3(256), 0, stream>>>(
      eWih, eWhh, dWih, dWhh, thW0, thW1, clW0, clW1, ws);
  encdec_kernel<<<dim3(128), dim3(512), 0, stream>>>(
      xf, yt, pp, ebih, ebhh, dbih, dbhh, thb0, thb1, clb0, clb1, ws, outp);
}

// Round 5
// 2053.307 us; speedup vs baseline: 1.2450x; 1.2450x over previous
//
#include <hip/hip_runtime.h>

typedef __bf16 v8bf __attribute__((ext_vector_type(8)));
typedef float v4f __attribute__((ext_vector_type(4)));
typedef unsigned short u16;
typedef unsigned int u32;

#define DEVI __device__ __forceinline__

constexpr int LX = 168, FF = 64;
constexpr int LY = 72, FT = 22, FOUTC = 10;
constexpr int HID = 256;
constexpr int HSTR = 264;   // u16/row for h tiles (528B = 33*16)
constexpr int UST2 = 40;    // u16/row for decoder input tiles
constexpr int A1STR = 264;  // u16/row for a1

// bf16 weight cache layout in d_ws (u16 element offsets; all 16B-aligned)
constexpr int W_EWIH = 0;                      // 768*64
constexpr int W_EWHH = 49152;                  // 768*256
constexpr int W_DWIH = 245760;                 // 768*32
constexpr int W_DWHH = 270336;                 // 768*256
constexpr int W_THW0 = 466944;                 // 128*256
constexpr int W_THW1 = 499712;                 // 2*128
constexpr int W_CLW0 = 499968;                 // 128*256
constexpr int W_CLW1 = 532736;                 // 8*128
constexpr int W_TOTAL = 533760;                // ~1.04 MB as u16

DEVI u16 f2bf(float f) {
  u32 x; __builtin_memcpy(&x, &f, 4);
  return (u16)((x + 0x7FFFu + ((x >> 16) & 1u)) >> 16);  // RNE
}
DEVI float sigm(float x) { return 1.f / (1.f + __expf(-x)); }
DEVI float tanh_(float x) {
  float e = __expf(-2.f * fabsf(x));
  return copysignf((1.f - e) / (1.f + e), x);
}
DEVI float smelu_(float x) {
  if (x >= 1.1f) return x;
  if (x <= -1.1f) return 0.f;
  float u = x + 1.1f;
  return u * u * (1.f / 4.4f);
}
DEVI v8bf ld8(const u16* p) { return *reinterpret_cast<const v8bf*>(p); }
DEVI v4f ldw(const u16* p) { return *reinterpret_cast<const v4f*>(p); }  // 16B raw
DEVI v8bf asbf(v4f x) { return __builtin_bit_cast(v8bf, x); }
DEVI v4f mfma16(v8bf a, v8bf b, v4f c) {
  return __builtin_amdgcn_mfma_f32_16x16x32_bf16(a, b, c, 0, 0, 0);
}
DEVI v8bf cvtf4(float4 lo, float4 hi) {
  v8bf r;
  r[0] = (__bf16)lo.x; r[1] = (__bf16)lo.y; r[2] = (__bf16)lo.z; r[3] = (__bf16)lo.w;
  r[4] = (__bf16)hi.x; r[5] = (__bf16)hi.y; r[6] = (__bf16)hi.z; r[7] = (__bf16)hi.w;
  return r;
}

// ---- prologue: convert all weight matrices f32 -> bf16 into d_ws ----
__global__ void cvt_weights(const float* __restrict__ eWih, const float* __restrict__ eWhh,
                            const float* __restrict__ dWih, const float* __restrict__ dWhh,
                            const float* __restrict__ thW0, const float* __restrict__ thW1,
                            const float* __restrict__ clW0, const float* __restrict__ clW1,
                            u16* __restrict__ ws) {
  const int i = blockIdx.x * 256 + threadIdx.x;
  if (i >= W_TOTAL) return;
  const float* src; int off;
  if      (i < W_EWHH) { src = eWih; off = W_EWIH; }
  else if (i < W_DWIH) { src = eWhh; off = W_EWHH; }
  else if (i < W_DWHH) { src = dWih; off = W_DWIH; }
  else if (i < W_THW0) { src = dWhh; off = W_DWHH; }
  else if (i < W_THW1) { src = thW0; off = W_THW0; }
  else if (i < W_CLW0) { src = thW1; off = W_THW1; }
  else if (i < W_CLW1) { src = clW0; off = W_CLW0; }
  else                 { src = clW1; off = W_CLW1; }
  ws[i] = f2bf(src[i - off]);
}

__global__ __launch_bounds__(512, 2) void encdec_kernel(
    const float* __restrict__ xf, const float* __restrict__ yt, const float* __restrict__ pp,
    const float* __restrict__ ebih, const float* __restrict__ ebhh,
    const float* __restrict__ dbih, const float* __restrict__ dbhh,
    const float* __restrict__ thb0, const float* __restrict__ thb1,
    const float* __restrict__ clb0, const float* __restrict__ clb1,
    const u16* __restrict__ ws, float* __restrict__ outp) {
  __shared__ __align__(16) u16 hls[2][16 * HSTR];   // double-buffered h (bf16)
  __shared__ __align__(16) u16 uls[2][16 * UST2];   // double-buffered dec input
  __shared__ __align__(16) u16 a1buf[16 * A1STR];

  const u16* eWih = ws + W_EWIH;
  const u16* eWhh = ws + W_EWHH;
  const u16* dWih = ws + W_DWIH;
  const u16* dWhh = ws + W_DWHH;
  const u16* thW0 = ws + W_THW0;
  const u16* thW1 = ws + W_THW1;
  const u16* clW0 = ws + W_CLW0;
  const u16* clW1 = ws + W_CLW1;

  const int tid = threadIdx.x;
  const int wave = tid >> 6;
  const int lane = tid & 63;
  const int col16 = lane & 15;
  const int quad = lane >> 4;
  const int n0 = blockIdx.x * 16;

  for (int idx = tid; idx < 16 * HSTR; idx += 512) hls[0][idx] = 0;

  float hreg[2][4];
#pragma unroll
  for (int j = 0; j < 2; ++j)
#pragma unroll
    for (int r = 0; r < 4; ++r) hreg[j][r] = 0.f;

  // Persistent Whh fragments for the z,n gate tiles (i=2..5): loaded once per
  // phase, laundered via empty asm so the allocator CANNOT rematerialize the
  // loads inside the recurrence loop (r3/r4 post-mortem: VGPR=128 showed it
  // collapsed all weight buffers back into serialized just-in-time loads).
  v4f wzn[4][8];

  // ================= encoder phase =================
  {
    float bs01[2], bs23[2], bi45[2], bh45[2];
#pragma unroll
    for (int i = 0; i < 2; ++i) {
      const int m0 = (wave + 8 * i) * 16 + col16;
      const int m2 = (wave + 8 * (i + 2)) * 16 + col16;
      const int m4 = (wave + 8 * (i + 4)) * 16 + col16;
      bs01[i] = ebih[m0] + ebhh[m0];
      bs23[i] = ebih[m2] + ebhh[m2];
      bi45[i] = ebih[m4];
      bh45[i] = ebhh[m4];
    }
#pragma unroll
    for (int i = 0; i < 4; ++i) {
      const u16* p = eWhh + (size_t)((wave + 8 * (i + 2)) * 16 + col16) * HID + quad * 8;
#pragma unroll
      for (int k = 0; k < 8; ++k) {
        wzn[i][k] = ldw(p + k * 32);
        asm("" : "+v"(wzn[i][k]));
      }
    }
    const float* xbase = xf + (size_t)(n0 + col16) * LX * FF + quad * 8;
    __syncthreads();  // h zero-init visible

#pragma unroll 1
    for (int t = 0; t < LX; ++t) {
      const float* xr = xbase + (size_t)t * FF;
      const float4 x0 = *(const float4*)(xr);
      const float4 x1 = *(const float4*)(xr + 4);
      const float4 x2 = *(const float4*)(xr + 32);
      const float4 x3 = *(const float4*)(xr + 36);
      const u16* hb = hls[t & 1] + col16 * HSTR + quad * 8;
      const v8bf xa0 = cvtf4(x0, x1);
      const v8bf xa1 = cvtf4(x2, x3);

      float rg[2][4], zg[2][4];
      // r tiles (i=0,1): Whh fully streamed from L2
#pragma unroll
      for (int i = 0; i < 2; ++i) {
        const int m = (wave + 8 * i) * 16 + col16;
        const u16* ph = eWhh + (size_t)m * HID + quad * 8;
        const u16* pw = eWih + (size_t)m * FF + quad * 8;
        v8bf wh[8];
#pragma unroll
        for (int k = 0; k < 8; ++k) wh[k] = ld8(ph + k * 32);
        const v8bf wi0 = ld8(pw), wi1 = ld8(pw + 32);
        v4f acc = {0.f, 0.f, 0.f, 0.f};
#pragma unroll
        for (int k = 0; k < 8; ++k) acc = mfma16(ld8(hb + k * 32), wh[k], acc);
        acc = mfma16(xa0, wi0, acc);
        acc = mfma16(xa1, wi1, acc);
#pragma unroll
        for (int r = 0; r < 4; ++r) rg[i][r] = sigm(acc[r] + bs01[i]);
      }
      // z tiles (i=2,3): Whh persistent
#pragma unroll
      for (int i = 0; i < 2; ++i) {
        const int m = (wave + 8 * (i + 2)) * 16 + col16;
        const u16* pw = eWih + (size_t)m * FF + quad * 8;
        const v8bf wi0 = ld8(pw), wi1 = ld8(pw + 32);
        v4f acc = {0.f, 0.f, 0.f, 0.f};
#pragma unroll
        for (int k = 0; k < 8; ++k) acc = mfma16(ld8(hb + k * 32), asbf(wzn[i][k]), acc);
        acc = mfma16(xa0, wi0, acc);
        acc = mfma16(xa1, wi1, acc);
#pragma unroll
        for (int r = 0; r < 4; ++r) zg[i][r] = sigm(acc[r] + bs23[i]);
      }
      // n tiles (i=4,5): Whh persistent; i_n and h_n kept separate
#pragma unroll
      for (int i = 0; i < 2; ++i) {
        const int m = (wave + 8 * (i + 4)) * 16 + col16;
        const u16* pw = eWih + (size_t)m * FF + quad * 8;
        const v8bf wi0 = ld8(pw), wi1 = ld8(pw + 32);
        v4f ah = {0.f, 0.f, 0.f, 0.f};
#pragma unroll
        for (int k = 0; k < 8; ++k) ah = mfma16(ld8(hb + k * 32), asbf(wzn[i + 2][k]), ah);
        v4f ai = {0.f, 0.f, 0.f, 0.f};
        ai = mfma16(xa0, wi0, ai);
        ai = mfma16(xa1, wi1, ai);
#pragma unroll
        for (int r = 0; r < 4; ++r) {
          const float ng = tanh_(ai[r] + bi45[i] + rg[i][r] * (ah[r] + bh45[i]));
          hreg[i][r] = (1.f - zg[i][r]) * ng + zg[i][r] * hreg[i][r];
        }
      }
#pragma unroll
      for (int j = 0; j < 2; ++j) {
        const int cidx = (wave + 8 * j) * 16 + col16;
#pragma unroll
        for (int r = 0; r < 4; ++r)
          hls[(t + 1) & 1][(quad * 4 + r) * HSTR + cidx] = f2bf(hreg[j][r]);
      }
      __syncthreads();
    }
  }
  // h_enc now in hls[LX & 1] == hls[0]

  // ================= decoder phase =================
  {
    float bs01[2], bs23[2], bi45[2], bh45[2], hb0[2];
#pragma unroll
    for (int i = 0; i < 2; ++i) {
      const int m0 = (wave + 8 * i) * 16 + col16;
      const int m2 = (wave + 8 * (i + 2)) * 16 + col16;
      const int m4 = (wave + 8 * (i + 4)) * 16 + col16;
      bs01[i] = dbih[m0] + dbhh[m0];
      bs23[i] = dbih[m2] + dbhh[m2];
      bi45[i] = dbih[m4];
      bh45[i] = dbhh[m4];
      const int ct = wave + 8 * i;
      const int ml = (ct & 7) * 16 + col16;
      hb0[i] = (ct < 8) ? thb0[ml] : clb0[ml];
    }
    const bool w1th = (col16 < 2);
    const bool w1cl = (col16 >= 2 && col16 < FOUTC);
    const float b1v = w1th ? thb1[col16] : (w1cl ? clb1[col16 - 2] : 0.f);
    // reload persistent z,n Whh from decoder weights
#pragma unroll
    for (int i = 0; i < 4; ++i) {
      const u16* p = dWhh + (size_t)((wave + 8 * (i + 2)) * 16 + col16) * HID + quad * 8;
#pragma unroll
      for (int k = 0; k < 8; ++k) {
        wzn[i][k] = ldw(p + k * 32);
        asm("" : "+v"(wzn[i][k]));
      }
    }
    const int srr = tid >> 5, scc = tid & 31;
    const size_t ybase = (size_t)(n0 + srr) * (LY + 1);
    {  // stage u_0 (src_t = 0)
      float v = (scc < FT) ? yt[ybase * FT + scc] : pp[ybase * FOUTC + (scc - FT)];
      uls[0][srr * UST2 + scc] = f2bf(v);
    }
    __syncthreads();

#pragma unroll 1
    for (int t = 0; t < LY; ++t) {
      float unext = 0.f;
      if (t + 1 < LY)
        unext = (scc < FT) ? yt[(ybase + t) * FT + scc]
                           : pp[(ybase + t) * FOUTC + (scc - FT)];
      const v8bf ua = ld8(uls[t & 1] + col16 * UST2 + quad * 8);
      const u16* hb = hls[t & 1] + col16 * HSTR + quad * 8;

      float rg[2][4], zg[2][4];
#pragma unroll
      for (int i = 0; i < 2; ++i) {  // r tiles streamed
        const int m = (wave + 8 * i) * 16 + col16;
        const u16* ph = dWhh + (size_t)m * HID + quad * 8;
        const u16* pw = dWih + (size_t)m * 32 + quad * 8;
        v8bf wh[8];
#pragma unroll
        for (int k = 0; k < 8; ++k) wh[k] = ld8(ph + k * 32);
        const v8bf wi0 = ld8(pw);
        v4f acc = {0.f, 0.f, 0.f, 0.f};
#pragma unroll
        for (int k = 0; k < 8; ++k) acc = mfma16(ld8(hb + k * 32), wh[k], acc);
        acc = mfma16(ua, wi0, acc);
#pragma unroll
        for (int r = 0; r < 4; ++r) rg[i][r] = sigm(acc[r] + bs01[i]);
      }
#pragma unroll
      for (int i = 0; i < 2; ++i) {  // z tiles persistent
        const int m = (wave + 8 * (i + 2)) * 16 + col16;
        const u16* pw = dWih + (size_t)m * 32 + quad * 8;
        const v8bf wi0 = ld8(pw);
        v4f acc = {0.f, 0.f, 0.f, 0.f};
#pragma unroll
        for (int k = 0; k < 8; ++k) acc = mfma16(ld8(hb + k * 32), asbf(wzn[i][k]), acc);
        acc = mfma16(ua, wi0, acc);
#pragma unroll
        for (int r = 0; r < 4; ++r) zg[i][r] = sigm(acc[r] + bs23[i]);
      }
#pragma unroll
      for (int i = 0; i < 2; ++i) {  // n tiles persistent
        const int m = (wave + 8 * (i + 4)) * 16 + col16;
        const u16* pw = dWih + (size_t)m * 32 + quad * 8;
        const v8bf wi0 = ld8(pw);
        v4f ah = {0.f, 0.f, 0.f, 0.f};
#pragma unroll
        for (int k = 0; k < 8; ++k) ah = mfma16(ld8(hb + k * 32), asbf(wzn[i + 2][k]), ah);
        v4f ai = {0.f, 0.f, 0.f, 0.f};
        ai = mfma16(ua, wi0, ai);
#pragma unroll
        for (int r = 0; r < 4; ++r) {
          const float ng = tanh_(ai[r] + bi45[i] + rg[i][r] * (ah[r] + bh45[i]));
          hreg[i][r] = (1.f - zg[i][r]) * ng + zg[i][r] * hreg[i][r];
        }
      }
#pragma unroll
      for (int j = 0; j < 2; ++j) {
        const int cidx = (wave + 8 * j) * 16 + col16;
#pragma unroll
        for (int r = 0; r < 4; ++r)
          hls[(t + 1) & 1][(quad * 4 + r) * HSTR + cidx] = f2bf(hreg[j][r]);
      }
      if (t + 1 < LY) uls[(t + 1) & 1][srr * UST2 + scc] = f2bf(unext);
      __syncthreads();  // Ba: h2 + u_{t+1} visible

      // head GEMM1: a1 = smelu(h2 @ W0^T + b0); tiles 0-7 temphr, 8-15 class
      {
        const u16* h2b = hls[(t + 1) & 1] + col16 * HSTR + quad * 8;
        v8bf ah2[8];
#pragma unroll
        for (int k = 0; k < 8; ++k) ah2[k] = ld8(h2b + k * 32);
#pragma unroll
        for (int i = 0; i < 2; ++i) {
          const int ct = wave + 8 * i;
          const u16* W0 = (ct < 8) ? thW0 : clW0;
          const u16* pw = W0 + (size_t)((ct & 7) * 16 + col16) * HID + quad * 8;
          v8bf wb[8];
#pragma unroll
          for (int k = 0; k < 8; ++k) wb[k] = ld8(pw + k * 32);
          v4f acc = {0.f, 0.f, 0.f, 0.f};
#pragma unroll
          for (int k = 0; k < 8; ++k) acc = mfma16(ah2[k], wb[k], acc);
#pragma unroll
          for (int r = 0; r < 4; ++r)
            a1buf[(quad * 4 + r) * A1STR + ct * 16 + col16] =
                f2bf(smelu_(acc[r] + hb0[i]));
        }
      }
      __syncthreads();  // Bb: a1 visible

      // head GEMM2 (wave 0): one K=256 pass, block-diag B = thW1 (+) clW1 (JIT)
      if (wave == 0) {
        const u16* arow = a1buf + col16 * A1STR + quad * 8;
        v4f acc = {0.f, 0.f, 0.f, 0.f};
#pragma unroll
        for (int kt = 0; kt < 8; ++kt) {
          v8bf b;
#pragma unroll
          for (int j = 0; j < 8; ++j) b[j] = (__bf16)0.0f;
          if (kt < 4) {
            if (w1th) b = ld8(thW1 + col16 * 128 + kt * 32 + quad * 8);
          } else {
            if (w1cl) b = ld8(clW1 + (col16 - 2) * 128 + (kt - 4) * 32 + quad * 8);
          }
          acc = mfma16(ld8(arow + kt * 32), b, acc);
        }
        if (col16 < FOUTC) {
#pragma unroll
          for (int r = 0; r < 4; ++r)
            outp[((size_t)(n0 + quad * 4 + r) * LY + t) * FOUTC + col16] =
                acc[r] + b1v;
        }
      }
      // wave0's a1 reads are protected: the next a1 write is after Ba(t+1),
      // which wave0 reaches only after finishing GEMM2(t).
    }
  }
}

extern "C" void kernel_launch(void* const* d_in, const int* in_sizes, int n_in,
                              void* d_out, int out_size, void* d_ws, size_t ws_size,
                              hipStream_t stream) {
  (void)in_sizes; (void)n_in; (void)ws_size; (void)out_size;
  const float* xf   = (const float*)d_in[0];
  // d_in[1] = x : unused by forward
  const float* yt   = (const float*)d_in[2];
  const float* pp   = (const float*)d_in[3];
  const float* eWih = (const float*)d_in[4];
  const float* eWhh = (const float*)d_in[5];
  const float* ebih = (const float*)d_in[6];
  const float* ebhh = (const float*)d_in[7];
  const float* dWih = (const float*)d_in[8];
  const float* dWhh = (const float*)d_in[9];
  const float* dbih = (const float*)d_in[10];
  const float* dbhh = (const float*)d_in[11];
  const float* thW0 = (const float*)d_in[12];
  const float* thb0 = (const float*)d_in[13];
  const float* thW1 = (const float*)d_in[14];
  const float* thb1 = (const float*)d_in[15];
  const float* clW0 = (const float*)d_in[16];
  const float* clb0 = (const float*)d_in[17];
  const float* clW1 = (const float*)d_in[18];
  const float* clb1 = (const float*)d_in[19];
  float* outp = (float*)d_out;
  u16* ws = (u16*)d_ws;  // needs W_TOTAL*2 ~= 1.04 MB of scratch

  cvt_weights<<<dim3((W_TOTAL + 255) / 256), dim3(256), 0, stream>>>(
      eWih, eWhh, dWih, dWhh, thW0, thW1, clW0, clW1, ws);
  encdec_kernel<<<dim3(128), dim3(512), 0, stream>>>(
      xf, yt, pp, ebih, ebhh, dbih, dbhh, thb0, thb1, clb0, clb1, ws, outp);
}

// Round 6
// 1658.712 us; speedup vs baseline: 1.5411x; 1.2379x over previous
//
#include <hip/hip_runtime.h>

typedef __bf16 v8bf __attribute__((ext_vector_type(8)));
typedef float v4f __attribute__((ext_vector_type(4)));
typedef float v4ff __attribute__((ext_vector_type(4)));
typedef unsigned short u16;
typedef unsigned int u32;

#define DEVI __device__ __forceinline__

constexpr int LX = 168, FF = 64;
constexpr int LY = 72, FT = 22, FOUTC = 10;
constexpr int HID = 256;
constexpr int HSTR = 264;   // u16/row h tiles (528B = 33*16)
constexpr int UST2 = 40;
constexpr int A1STR = 264;
constexpr int SSTR = 264;   // slab row stride (r-gate Whh rows 0..255)

// bf16 weight cache layout in d_ws (u16 element offsets; all 16B-aligned)
constexpr int W_EWIH = 0;                      // 768*64
constexpr int W_EWHH = 49152;                  // 768*256
constexpr int W_DWIH = 245760;                 // 768*32
constexpr int W_DWHH = 270336;                 // 768*256
constexpr int W_THW0 = 466944;                 // 128*256
constexpr int W_THW1 = 499712;                 // 2*128
constexpr int W_CLW0 = 499968;                 // 128*256
constexpr int W_CLW1 = 532736;                 // 8*128
constexpr int W_TOTAL = 533760;

DEVI u16 f2bf(float f) {
  u32 x; __builtin_memcpy(&x, &f, 4);
  return (u16)((x + 0x7FFFu + ((x >> 16) & 1u)) >> 16);  // RNE
}
DEVI float sigm(float x) { return 1.f / (1.f + __expf(-x)); }
DEVI float tanh_(float x) {
  float e = __expf(-2.f * fabsf(x));
  return copysignf((1.f - e) / (1.f + e), x);
}
DEVI float smelu_(float x) {
  if (x >= 1.1f) return x;
  if (x <= -1.1f) return 0.f;
  float u = x + 1.1f;
  return u * u * (1.f / 4.4f);
}
DEVI v8bf ld8(const u16* p) { return *reinterpret_cast<const v8bf*>(p); }
DEVI v4f ldw(const u16* p) { return *reinterpret_cast<const v4f*>(p); }
DEVI v8bf asbf(v4f x) { return __builtin_bit_cast(v8bf, x); }
DEVI void pin(v4f& x) { asm("" : "+v"(x)); }       // defeat rematerialization
DEVI void pinf(v4ff& x) { asm("" : "+v"(x)); }
DEVI v4f mfma16(v8bf a, v8bf b, v4f c) {
  return __builtin_amdgcn_mfma_f32_16x16x32_bf16(a, b, c, 0, 0, 0);
}
DEVI v8bf cvt2f(v4ff lo, v4ff hi) {
  v8bf r;
#pragma unroll
  for (int j = 0; j < 4; ++j) { r[j] = (__bf16)lo[j]; r[4 + j] = (__bf16)hi[j]; }
  return r;
}

// ---- prologue: convert all weight matrices f32 -> bf16 into d_ws ----
__global__ void cvt_weights(const float* __restrict__ eWih, const float* __restrict__ eWhh,
                            const float* __restrict__ dWih, const float* __restrict__ dWhh,
                            const float* __restrict__ thW0, const float* __restrict__ thW1,
                            const float* __restrict__ clW0, const float* __restrict__ clW1,
                            u16* __restrict__ ws) {
  const int i = blockIdx.x * 256 + threadIdx.x;
  if (i >= W_TOTAL) return;
  const float* src; int off;
  if      (i < W_EWHH) { src = eWih; off = W_EWIH; }
  else if (i < W_DWIH) { src = eWhh; off = W_EWHH; }
  else if (i < W_DWHH) { src = dWih; off = W_DWIH; }
  else if (i < W_THW0) { src = dWhh; off = W_DWHH; }
  else if (i < W_THW1) { src = thW0; off = W_THW0; }
  else if (i < W_CLW0) { src = thW1; off = W_THW1; }
  else if (i < W_CLW1) { src = clW0; off = W_CLW0; }
  else                 { src = clW1; off = W_CLW1; }
  ws[i] = f2bf(src[i - off]);
}

__global__ __launch_bounds__(256, 1) void encdec_kernel(
    const float* __restrict__ xf, const float* __restrict__ yt, const float* __restrict__ pp,
    const float* __restrict__ ebih, const float* __restrict__ ebhh,
    const float* __restrict__ dbih, const float* __restrict__ dbhh,
    const float* __restrict__ thb0, const float* __restrict__ thb1,
    const float* __restrict__ clb0, const float* __restrict__ clb1,
    const u16* __restrict__ ws, float* __restrict__ outp) {
  __shared__ __align__(16) u16 slab[256 * SSTR];   // r-gate Whh rows (132 KB)
  __shared__ __align__(16) u16 hls[2][16 * HSTR];
  __shared__ __align__(16) u16 uls[2][16 * UST2];
  __shared__ __align__(16) u16 a1buf[16 * A1STR];

  const u16* eWih = ws + W_EWIH;
  const u16* eWhh = ws + W_EWHH;
  const u16* dWih = ws + W_DWIH;
  const u16* dWhh = ws + W_DWHH;
  const u16* thW0 = ws + W_THW0;
  const u16* thW1 = ws + W_THW1;
  const u16* clW0 = ws + W_CLW0;
  const u16* clW1 = ws + W_CLW1;

  const int tid = threadIdx.x;
  const int wave = tid >> 6;        // 4 waves
  const int lane = tid & 63;
  const int col16 = lane & 15;
  const int quad = lane >> 4;
  const int n0 = blockIdx.x * 16;

  for (int i = tid; i < 16 * HSTR; i += 256) hls[0][i] = 0;

  float hreg[4][4];
#pragma unroll
  for (int j = 0; j < 4; ++j)
#pragma unroll
    for (int r = 0; r < 4; ++r) hreg[j][r] = 0.f;

  // Persistent (laundered -> AGPR-eligible): z,n Whh (256 regs) + Wih (96).
  v4f wz[4][8], wn[4][8];
  v4f wir[4][2], wiz[4][2], win[4][2];
  float bsr[4], bsz[4], bin_[4], bhn[4];

  // ================= encoder phase =================
  {
    // stage r-gate Whh rows 0..255 into LDS slab (once)
    for (int i = tid; i < 256 * 32; i += 256) {
      const int row = i >> 5, kb = (i & 31) << 3;
      *reinterpret_cast<v8bf*>(&slab[row * SSTR + kb]) = ld8(eWhh + row * HID + kb);
    }
#pragma unroll
    for (int j = 0; j < 4; ++j) {
      const int c = wave + 4 * j;
      const int mr = c * 16 + col16, mz = 256 + mr, mn = 512 + mr;
#pragma unroll
      for (int k = 0; k < 8; ++k) {
        wz[j][k] = ldw(eWhh + (size_t)mz * HID + k * 32 + quad * 8); pin(wz[j][k]);
        wn[j][k] = ldw(eWhh + (size_t)mn * HID + k * 32 + quad * 8); pin(wn[j][k]);
      }
      wir[j][0] = ldw(eWih + (size_t)mr * FF + quad * 8);      pin(wir[j][0]);
      wir[j][1] = ldw(eWih + (size_t)mr * FF + 32 + quad * 8); pin(wir[j][1]);
      wiz[j][0] = ldw(eWih + (size_t)mz * FF + quad * 8);      pin(wiz[j][0]);
      wiz[j][1] = ldw(eWih + (size_t)mz * FF + 32 + quad * 8); pin(wiz[j][1]);
      win[j][0] = ldw(eWih + (size_t)mn * FF + quad * 8);      pin(win[j][0]);
      win[j][1] = ldw(eWih + (size_t)mn * FF + 32 + quad * 8); pin(win[j][1]);
      bsr[j] = ebih[mr] + ebhh[mr];
      bsz[j] = ebih[mz] + ebhh[mz];
      bin_[j] = ebih[mn];
      bhn[j] = ebhh[mn];
    }
    const float* xbase = xf + (size_t)(n0 + col16) * LX * FF + quad * 8;
    v4ff xr0 = *(const v4ff*)(xbase);
    v4ff xr1 = *(const v4ff*)(xbase + 4);
    v4ff xr2 = *(const v4ff*)(xbase + 32);
    v4ff xr3 = *(const v4ff*)(xbase + 36);
    __syncthreads();  // slab + h-init visible

#pragma unroll 1
    for (int t = 0; t < LX; ++t) {
      v4ff xn0, xn1, xn2, xn3;
      if (t + 1 < LX) {  // prefetch next x across this whole step (HBM latency)
        const float* xn = xbase + (size_t)(t + 1) * FF;
        xn0 = *(const v4ff*)(xn);      pinf(xn0);
        xn1 = *(const v4ff*)(xn + 4);  pinf(xn1);
        xn2 = *(const v4ff*)(xn + 32); pinf(xn2);
        xn3 = *(const v4ff*)(xn + 36); pinf(xn3);
      }
      const u16* hb = hls[t & 1] + col16 * HSTR + quad * 8;
      v8bf a[8];
#pragma unroll
      for (int k = 0; k < 8; ++k) a[k] = ld8(hb + k * 32);
      const v8bf xa0 = cvt2f(xr0, xr1);
      const v8bf xa1 = cvt2f(xr2, xr3);

      float rg[4][4], zg[4][4];
#pragma unroll
      for (int j = 0; j < 4; ++j) {  // r tiles: Whh frags from LDS slab
        const int c = wave + 4 * j;
        const u16* sp = slab + (c * 16 + col16) * SSTR + quad * 8;
        v4f acc = {0.f, 0.f, 0.f, 0.f};
#pragma unroll
        for (int k = 0; k < 8; ++k) acc = mfma16(a[k], ld8(sp + k * 32), acc);
        acc = mfma16(xa0, asbf(wir[j][0]), acc);
        acc = mfma16(xa1, asbf(wir[j][1]), acc);
#pragma unroll
        for (int r = 0; r < 4; ++r) rg[j][r] = sigm(acc[r] + bsr[j]);
      }
#pragma unroll
      for (int j = 0; j < 4; ++j) {  // z tiles: persistent
        v4f acc = {0.f, 0.f, 0.f, 0.f};
#pragma unroll
        for (int k = 0; k < 8; ++k) acc = mfma16(a[k], asbf(wz[j][k]), acc);
        acc = mfma16(xa0, asbf(wiz[j][0]), acc);
        acc = mfma16(xa1, asbf(wiz[j][1]), acc);
#pragma unroll
        for (int r = 0; r < 4; ++r) zg[j][r] = sigm(acc[r] + bsz[j]);
      }
#pragma unroll
      for (int j = 0; j < 4; ++j) {  // n tiles: persistent; i_n, h_n separate
        v4f ah = {0.f, 0.f, 0.f, 0.f};
#pragma unroll
        for (int k = 0; k < 8; ++k) ah = mfma16(a[k], asbf(wn[j][k]), ah);
        v4f ai = {0.f, 0.f, 0.f, 0.f};
        ai = mfma16(xa0, asbf(win[j][0]), ai);
        ai = mfma16(xa1, asbf(win[j][1]), ai);
#pragma unroll
        for (int r = 0; r < 4; ++r) {
          const float ng = tanh_(ai[r] + bin_[j] + rg[j][r] * (ah[r] + bhn[j]));
          hreg[j][r] = (1.f - zg[j][r]) * ng + zg[j][r] * hreg[j][r];
        }
      }
#pragma unroll
      for (int j = 0; j < 4; ++j) {
        const int cidx = (wave + 4 * j) * 16 + col16;
#pragma unroll
        for (int r = 0; r < 4; ++r)
          hls[(t + 1) & 1][(quad * 4 + r) * HSTR + cidx] = f2bf(hreg[j][r]);
      }
      __syncthreads();
      xr0 = xn0; xr1 = xn1; xr2 = xn2; xr3 = xn3;
    }
  }
  // h_enc in hls[LX & 1] == hls[0]

  // ================= decoder phase =================
  {
    // restage slab with dWhh r-gate rows (all encoder slab reads are behind
    // the final encoder barrier)
    for (int i = tid; i < 256 * 32; i += 256) {
      const int row = i >> 5, kb = (i & 31) << 3;
      *reinterpret_cast<v8bf*>(&slab[row * SSTR + kb]) = ld8(dWhh + row * HID + kb);
    }
    float hb0[4];
#pragma unroll
    for (int j = 0; j < 4; ++j) {
      const int c = wave + 4 * j;
      const int mr = c * 16 + col16, mz = 256 + mr, mn = 512 + mr;
#pragma unroll
      for (int k = 0; k < 8; ++k) {
        wz[j][k] = ldw(dWhh + (size_t)mz * HID + k * 32 + quad * 8); pin(wz[j][k]);
        wn[j][k] = ldw(dWhh + (size_t)mn * HID + k * 32 + quad * 8); pin(wn[j][k]);
      }
      wir[j][0] = ldw(dWih + (size_t)mr * 32 + quad * 8); pin(wir[j][0]);
      wiz[j][0] = ldw(dWih + (size_t)mz * 32 + quad * 8); pin(wiz[j][0]);
      win[j][0] = ldw(dWih + (size_t)mn * 32 + quad * 8); pin(win[j][0]);
      bsr[j] = dbih[mr] + dbhh[mr];
      bsz[j] = dbih[mz] + dbhh[mz];
      bin_[j] = dbih[mn];
      bhn[j] = dbhh[mn];
      const int ml = (c & 7) * 16 + col16;
      hb0[j] = (c < 8) ? thb0[ml] : clb0[ml];
    }
    const bool w1th = (col16 < 2);
    const bool w1cl = (col16 >= 2 && col16 < FOUTC);
    const float b1v = w1th ? thb1[col16] : (w1cl ? clb1[col16 - 2] : 0.f);

    // stage u_0 (src_t = 0): 512 elems, 2 per thread
#pragma unroll
    for (int s = 0; s < 2; ++s) {
      const int i = tid + 256 * s;
      const int rr = i >> 5, cc = i & 31;
      const size_t yb = (size_t)(n0 + rr) * (LY + 1);
      const float v = (cc < FT) ? yt[yb * FT + cc] : pp[yb * FOUTC + (cc - FT)];
      uls[0][rr * UST2 + cc] = f2bf(v);
    }
    __syncthreads();  // slab + u_0 visible

#pragma unroll 1
    for (int t = 0; t < LY; ++t) {
      float un[2];
#pragma unroll
      for (int s = 0; s < 2; ++s) {
        un[s] = 0.f;
        if (t + 1 < LY) {
          const int i = tid + 256 * s;
          const int rr = i >> 5, cc = i & 31;
          const size_t yb = (size_t)(n0 + rr) * (LY + 1) + t;
          un[s] = (cc < FT) ? yt[yb * FT + cc] : pp[yb * FOUTC + (cc - FT)];
        }
      }
      const v8bf ua = ld8(uls[t & 1] + col16 * UST2 + quad * 8);
      const u16* hb = hls[t & 1] + col16 * HSTR + quad * 8;
      v8bf a[8];
#pragma unroll
      for (int k = 0; k < 8; ++k) a[k] = ld8(hb + k * 32);

      float rg[4][4], zg[4][4];
#pragma unroll
      for (int j = 0; j < 4; ++j) {  // r tiles from slab
        const int c = wave + 4 * j;
        const u16* sp = slab + (c * 16 + col16) * SSTR + quad * 8;
        v4f acc = {0.f, 0.f, 0.f, 0.f};
#pragma unroll
        for (int k = 0; k < 8; ++k) acc = mfma16(a[k], ld8(sp + k * 32), acc);
        acc = mfma16(ua, asbf(wir[j][0]), acc);
#pragma unroll
        for (int r = 0; r < 4; ++r) rg[j][r] = sigm(acc[r] + bsr[j]);
      }
#pragma unroll
      for (int j = 0; j < 4; ++j) {
        v4f acc = {0.f, 0.f, 0.f, 0.f};
#pragma unroll
        for (int k = 0; k < 8; ++k) acc = mfma16(a[k], asbf(wz[j][k]), acc);
        acc = mfma16(ua, asbf(wiz[j][0]), acc);
#pragma unroll
        for (int r = 0; r < 4; ++r) zg[j][r] = sigm(acc[r] + bsz[j]);
      }
#pragma unroll
      for (int j = 0; j < 4; ++j) {
        v4f ah = {0.f, 0.f, 0.f, 0.f};
#pragma unroll
        for (int k = 0; k < 8; ++k) ah = mfma16(a[k], asbf(wn[j][k]), ah);
        v4f ai = {0.f, 0.f, 0.f, 0.f};
        ai = mfma16(ua, asbf(win[j][0]), ai);
#pragma unroll
        for (int r = 0; r < 4; ++r) {
          const float ng = tanh_(ai[r] + bin_[j] + rg[j][r] * (ah[r] + bhn[j]));
          hreg[j][r] = (1.f - zg[j][r]) * ng + zg[j][r] * hreg[j][r];
        }
      }
#pragma unroll
      for (int j = 0; j < 4; ++j) {
        const int cidx = (wave + 4 * j) * 16 + col16;
#pragma unroll
        for (int r = 0; r < 4; ++r)
          hls[(t + 1) & 1][(quad * 4 + r) * HSTR + cidx] = f2bf(hreg[j][r]);
      }
      if (t + 1 < LY) {
#pragma unroll
        for (int s = 0; s < 2; ++s) {
          const int i = tid + 256 * s;
          uls[(t + 1) & 1][(i >> 5) * UST2 + (i & 31)] = f2bf(un[s]);
        }
      }
      __syncthreads();  // Ba: h2 + u_{t+1} visible

      // head GEMM1: each wave 4 head tiles (c<8: temphr, else class)
      {
        const u16* h2b = hls[(t + 1) & 1] + col16 * HSTR + quad * 8;
        v8bf ah2[8];
#pragma unroll
        for (int k = 0; k < 8; ++k) ah2[k] = ld8(h2b + k * 32);
#pragma unroll
        for (int j = 0; j < 4; ++j) {
          const int c = wave + 4 * j;
          const u16* W0 = (c < 8) ? thW0 : clW0;
          const u16* pw = W0 + (size_t)((c & 7) * 16 + col16) * HID + quad * 8;
          v8bf wb[8];
#pragma unroll
          for (int k = 0; k < 8; ++k) wb[k] = ld8(pw + k * 32);
          v4f acc = {0.f, 0.f, 0.f, 0.f};
#pragma unroll
          for (int k = 0; k < 8; ++k) acc = mfma16(ah2[k], wb[k], acc);
#pragma unroll
          for (int r = 0; r < 4; ++r)
            a1buf[(quad * 4 + r) * A1STR + c * 16 + col16] =
                f2bf(smelu_(acc[r] + hb0[j]));
        }
      }
      __syncthreads();  // Bb: a1 visible

      // head GEMM2 (wave 0): K=256 pass, block-diag B = thW1 (+) clW1
      if (wave == 0) {
        const u16* arow = a1buf + col16 * A1STR + quad * 8;
        v4f acc = {0.f, 0.f, 0.f, 0.f};
#pragma unroll
        for (int kt = 0; kt < 8; ++kt) {
          v8bf b;
#pragma unroll
          for (int j = 0; j < 8; ++j) b[j] = (__bf16)0.0f;
          if (kt < 4) {
            if (w1th) b = ld8(thW1 + col16 * 128 + kt * 32 + quad * 8);
          } else {
            if (w1cl) b = ld8(clW1 + (col16 - 2) * 128 + (kt - 4) * 32 + quad * 8);
          }
          acc = mfma16(ld8(arow + kt * 32), b, acc);
        }
        if (col16 < FOUTC) {
#pragma unroll
          for (int r = 0; r < 4; ++r)
            outp[((size_t)(n0 + quad * 4 + r) * LY + t) * FOUTC + col16] =
                acc[r] + b1v;
        }
      }
      // wave0's a1 reads precede the next a1 write (behind Ba(t+1)+GEMM1).
    }
  }
}

extern "C" void kernel_launch(void* const* d_in, const int* in_sizes, int n_in,
                              void* d_out, int out_size, void* d_ws, size_t ws_size,
                              hipStream_t stream) {
  (void)in_sizes; (void)n_in; (void)ws_size; (void)out_size;
  const float* xf   = (const float*)d_in[0];
  // d_in[1] = x : unused by forward
  const float* yt   = (const float*)d_in[2];
  const float* pp   = (const float*)d_in[3];
  const float* eWih = (const float*)d_in[4];
  const float* eWhh = (const float*)d_in[5];
  const float* ebih = (const float*)d_in[6];
  const float* ebhh = (const float*)d_in[7];
  const float* dWih = (const float*)d_in[8];
  const float* dWhh = (const float*)d_in[9];
  const float* dbih = (const float*)d_in[10];
  const float* dbhh = (const float*)d_in[11];
  const float* thW0 = (const float*)d_in[12];
  const float* thb0 = (const float*)d_in[13];
  const float* thW1 = (const float*)d_in[14];
  const float* thb1 = (const float*)d_in[15];
  const float* clW0 = (const float*)d_in[16];
  const float* clb0 = (const float*)d_in[17];
  const float* clW1 = (const float*)d_in[18];
  const float* clb1 = (const float*)d_in[19];
  float* outp = (float*)d_out;
  u16* ws = (u16*)d_ws;  // needs W_TOTAL*2 ~= 1.04 MB of scratch

  cvt_weights<<<dim3((W_TOTAL + 255) / 256), dim3(256), 0, stream>>>(
      eWih, eWhh, dWih, dWhh, thW0, thW1, clW0, clW1, ws);
  encdec_kernel<<<dim3(128), dim3(256), 0, stream>>>(
      xf, yt, pp, ebih, ebhh, dbih, dbhh, thb0, thb1, clb0, clb1, ws, outp);
}

// Round 7
// 1474.770 us; speedup vs baseline: 1.7334x; 1.1247x over previous
//
#include <hip/hip_runtime.h>

typedef __bf16 v8bf __attribute__((ext_vector_type(8)));
typedef float v4f __attribute__((ext_vector_type(4)));
typedef float v4ff __attribute__((ext_vector_type(4)));
typedef unsigned short u16;
typedef unsigned int u32;

#define DEVI __device__ __forceinline__

constexpr int LX = 168, FF = 64;
constexpr int LY = 72, FT = 22, FOUTC = 10;
constexpr int HID = 256;
constexpr int HSTR = 264;   // u16/row h tiles (528B = 33*16)
constexpr int UST2 = 40;
constexpr int A1STR = 264;
constexpr int SSTR = 264;   // slab row stride (r-gate Whh rows 0..255)

// bf16 weight cache layout in d_ws (u16 element offsets; all 16B-aligned)
constexpr int W_EWIH = 0;                      // 768*64
constexpr int W_EWHH = 49152;                  // 768*256
constexpr int W_DWIH = 245760;                 // 768*32
constexpr int W_DWHH = 270336;                 // 768*256
constexpr int W_THW0 = 466944;                 // 128*256
constexpr int W_THW1 = 499712;                 // 2*128
constexpr int W_CLW0 = 499968;                 // 128*256
constexpr int W_CLW1 = 532736;                 // 8*128
constexpr int W_TOTAL = 533760;

DEVI u16 f2bf(float f) {
  u32 x; __builtin_memcpy(&x, &f, 4);
  return (u16)((x + 0x7FFFu + ((x >> 16) & 1u)) >> 16);  // RNE (keep: h feeds recurrence)
}
// fast sigmoid/tanh: v_rcp instead of precise-division sequence (r6 post-mortem:
// 32 precise divs/lane/step = ~320 VALU instrs + 40-cyc dependent chains)
DEVI float sigm(float x) { return __builtin_amdgcn_rcpf(1.f + __expf(-x)); }
DEVI float tanh_(float x) {
  float e = __expf(-2.f * fabsf(x));
  return copysignf((1.f - e) * __builtin_amdgcn_rcpf(1.f + e), x);
}
DEVI float smelu_(float x) {
  if (x >= 1.1f) return x;
  if (x <= -1.1f) return 0.f;
  float u = x + 1.1f;
  return u * u * (1.f / 4.4f);
}
DEVI v8bf ld8(const u16* p) { return *reinterpret_cast<const v8bf*>(p); }
DEVI v4f ldw(const u16* p) { return *reinterpret_cast<const v4f*>(p); }
DEVI v8bf asbf(v4f x) { return __builtin_bit_cast(v8bf, x); }
DEVI void pin(v4f& x) { asm("" : "+v"(x)); }       // defeat rematerialization
DEVI void pinf(v4ff& x) { asm("" : "+v"(x)); }
DEVI v4f mfma16(v8bf a, v8bf b, v4f c) {
  return __builtin_amdgcn_mfma_f32_16x16x32_bf16(a, b, c, 0, 0, 0);
}
DEVI v8bf cvt2f(v4ff lo, v4ff hi) {
  v8bf r;
#pragma unroll
  for (int j = 0; j < 4; ++j) { r[j] = (__bf16)lo[j]; r[4 + j] = (__bf16)hi[j]; }
  return r;
}

// ---- prologue: convert all weight matrices f32 -> bf16 into d_ws ----
__global__ void cvt_weights(const float* __restrict__ eWih, const float* __restrict__ eWhh,
                            const float* __restrict__ dWih, const float* __restrict__ dWhh,
                            const float* __restrict__ thW0, const float* __restrict__ thW1,
                            const float* __restrict__ clW0, const float* __restrict__ clW1,
                            u16* __restrict__ ws) {
  const int i = blockIdx.x * 256 + threadIdx.x;
  if (i >= W_TOTAL) return;
  const float* src; int off;
  if      (i < W_EWHH) { src = eWih; off = W_EWIH; }
  else if (i < W_DWIH) { src = eWhh; off = W_EWHH; }
  else if (i < W_DWHH) { src = dWih; off = W_DWIH; }
  else if (i < W_THW0) { src = dWhh; off = W_DWHH; }
  else if (i < W_THW1) { src = thW0; off = W_THW0; }
  else if (i < W_CLW0) { src = thW1; off = W_THW1; }
  else if (i < W_CLW1) { src = clW0; off = W_CLW0; }
  else                 { src = clW1; off = W_CLW1; }
  ws[i] = f2bf(src[i - off]);
}

__global__ __launch_bounds__(256, 1) void encdec_kernel(
    const float* __restrict__ xf, const float* __restrict__ yt, const float* __restrict__ pp,
    const float* __restrict__ ebih, const float* __restrict__ ebhh,
    const float* __restrict__ dbih, const float* __restrict__ dbhh,
    const float* __restrict__ thb0, const float* __restrict__ thb1,
    const float* __restrict__ clb0, const float* __restrict__ clb1,
    const u16* __restrict__ ws, float* __restrict__ outp) {
  __shared__ __align__(16) u16 slab[256 * SSTR];   // r-gate Whh rows (132 KB)
  __shared__ __align__(16) u16 hls[2][16 * HSTR];
  __shared__ __align__(16) u16 uls[2][16 * UST2];
  __shared__ __align__(16) u16 a1buf[16 * A1STR];

  const u16* eWih = ws + W_EWIH;
  const u16* eWhh = ws + W_EWHH;
  const u16* dWih = ws + W_DWIH;
  const u16* dWhh = ws + W_DWHH;
  const u16* thW0 = ws + W_THW0;
  const u16* thW1 = ws + W_THW1;
  const u16* clW0 = ws + W_CLW0;
  const u16* clW1 = ws + W_CLW1;

  const int tid = threadIdx.x;
  const int wave = tid >> 6;        // 4 waves
  const int lane = tid & 63;
  const int col16 = lane & 15;
  const int quad = lane >> 4;
  const int n0 = blockIdx.x * 16;

  for (int i = tid; i < 16 * HSTR; i += 256) hls[0][i] = 0;

  float hreg[4][4];
#pragma unroll
  for (int j = 0; j < 4; ++j)
#pragma unroll
    for (int r = 0; r < 4; ++r) hreg[j][r] = 0.f;

  // Persistent (laundered -> AGPR-eligible): z,n Whh (256 regs) + Wih (96).
  v4f wz[4][8], wn[4][8];
  v4f wir[4][2], wiz[4][2], win[4][2];
  float bsr[4], bsz[4], bin_[4], bhn[4];

  // ================= encoder phase =================
  {
    // stage r-gate Whh rows 0..255 into LDS slab (once)
    for (int i = tid; i < 256 * 32; i += 256) {
      const int row = i >> 5, kb = (i & 31) << 3;
      *reinterpret_cast<v8bf*>(&slab[row * SSTR + kb]) = ld8(eWhh + row * HID + kb);
    }
#pragma unroll
    for (int j = 0; j < 4; ++j) {
      const int c = wave + 4 * j;
      const int mr = c * 16 + col16, mz = 256 + mr, mn = 512 + mr;
#pragma unroll
      for (int k = 0; k < 8; ++k) {
        wz[j][k] = ldw(eWhh + (size_t)mz * HID + k * 32 + quad * 8); pin(wz[j][k]);
        wn[j][k] = ldw(eWhh + (size_t)mn * HID + k * 32 + quad * 8); pin(wn[j][k]);
      }
      wir[j][0] = ldw(eWih + (size_t)mr * FF + quad * 8);      pin(wir[j][0]);
      wir[j][1] = ldw(eWih + (size_t)mr * FF + 32 + quad * 8); pin(wir[j][1]);
      wiz[j][0] = ldw(eWih + (size_t)mz * FF + quad * 8);      pin(wiz[j][0]);
      wiz[j][1] = ldw(eWih + (size_t)mz * FF + 32 + quad * 8); pin(wiz[j][1]);
      win[j][0] = ldw(eWih + (size_t)mn * FF + quad * 8);      pin(win[j][0]);
      win[j][1] = ldw(eWih + (size_t)mn * FF + 32 + quad * 8); pin(win[j][1]);
      bsr[j] = ebih[mr] + ebhh[mr];
      bsz[j] = ebih[mz] + ebhh[mz];
      bin_[j] = ebih[mn];
      bhn[j] = ebhh[mn];
    }
    const float* xbase = xf + (size_t)(n0 + col16) * LX * FF + quad * 8;
    v4ff xr0 = *(const v4ff*)(xbase);
    v4ff xr1 = *(const v4ff*)(xbase + 4);
    v4ff xr2 = *(const v4ff*)(xbase + 32);
    v4ff xr3 = *(const v4ff*)(xbase + 36);
    __syncthreads();  // slab + h-init visible

#pragma unroll 1
    for (int t = 0; t < LX; ++t) {
      v4ff xn0, xn1, xn2, xn3;
      if (t + 1 < LX) {  // prefetch next x across this whole step (HBM latency)
        const float* xn = xbase + (size_t)(t + 1) * FF;
        xn0 = *(const v4ff*)(xn);      pinf(xn0);
        xn1 = *(const v4ff*)(xn + 4);  pinf(xn1);
        xn2 = *(const v4ff*)(xn + 32); pinf(xn2);
        xn3 = *(const v4ff*)(xn + 36); pinf(xn3);
      }
      const u16* hb = hls[t & 1] + col16 * HSTR + quad * 8;
      v8bf a[8];
#pragma unroll
      for (int k = 0; k < 8; ++k) a[k] = ld8(hb + k * 32);
      const v8bf xa0 = cvt2f(xr0, xr1);
      const v8bf xa1 = cvt2f(xr2, xr3);

      // z tiles FIRST: pure register operands -> MFMAs issue right after a[];
      // the r-tiles' slab ds_reads land underneath this phase.
      float zg[4][4];
#pragma unroll
      for (int j = 0; j < 4; ++j) {
        v4f acc = {0.f, 0.f, 0.f, 0.f};
#pragma unroll
        for (int k = 0; k < 8; ++k) acc = mfma16(a[k], asbf(wz[j][k]), acc);
        acc = mfma16(xa0, asbf(wiz[j][0]), acc);
        acc = mfma16(xa1, asbf(wiz[j][1]), acc);
#pragma unroll
        for (int r = 0; r < 4; ++r) zg[j][r] = sigm(acc[r] + bsz[j]);
      }
      // n tiles h-part + i-part (persistent weights)
      v4f anh[4], ani[4];
#pragma unroll
      for (int j = 0; j < 4; ++j) {
        v4f ah = {0.f, 0.f, 0.f, 0.f};
#pragma unroll
        for (int k = 0; k < 8; ++k) ah = mfma16(a[k], asbf(wn[j][k]), ah);
        anh[j] = ah;
        v4f ai = {0.f, 0.f, 0.f, 0.f};
        ai = mfma16(xa0, asbf(win[j][0]), ai);
        ai = mfma16(xa1, asbf(win[j][1]), ai);
        ani[j] = ai;
      }
      // r tiles LAST (slab frags long since landed) + fused n-combine per tile
#pragma unroll
      for (int j = 0; j < 4; ++j) {
        const int c = wave + 4 * j;
        const u16* sp = slab + (c * 16 + col16) * SSTR + quad * 8;
        v4f acc = {0.f, 0.f, 0.f, 0.f};
#pragma unroll
        for (int k = 0; k < 8; ++k) acc = mfma16(a[k], ld8(sp + k * 32), acc);
        acc = mfma16(xa0, asbf(wir[j][0]), acc);
        acc = mfma16(xa1, asbf(wir[j][1]), acc);
#pragma unroll
        for (int r = 0; r < 4; ++r) {
          const float rg = sigm(acc[r] + bsr[j]);
          const float ng = tanh_(ani[j][r] + bin_[j] + rg * (anh[j][r] + bhn[j]));
          hreg[j][r] = (1.f - zg[j][r]) * ng + zg[j][r] * hreg[j][r];
        }
        const int cidx = c * 16 + col16;
#pragma unroll
        for (int r = 0; r < 4; ++r)
          hls[(t + 1) & 1][(quad * 4 + r) * HSTR + cidx] = f2bf(hreg[j][r]);
      }
      __syncthreads();
      xr0 = xn0; xr1 = xn1; xr2 = xn2; xr3 = xn3;
    }
  }
  // h_enc in hls[LX & 1] == hls[0]

  // ================= decoder phase =================
  {
    // restage slab with dWhh r-gate rows
    for (int i = tid; i < 256 * 32; i += 256) {
      const int row = i >> 5, kb = (i & 31) << 3;
      *reinterpret_cast<v8bf*>(&slab[row * SSTR + kb]) = ld8(dWhh + row * HID + kb);
    }
    float hb0[4];
#pragma unroll
    for (int j = 0; j < 4; ++j) {
      const int c = wave + 4 * j;
      const int mr = c * 16 + col16, mz = 256 + mr, mn = 512 + mr;
#pragma unroll
      for (int k = 0; k < 8; ++k) {
        wz[j][k] = ldw(dWhh + (size_t)mz * HID + k * 32 + quad * 8); pin(wz[j][k]);
        wn[j][k] = ldw(dWhh + (size_t)mn * HID + k * 32 + quad * 8); pin(wn[j][k]);
      }
      wir[j][0] = ldw(dWih + (size_t)mr * 32 + quad * 8); pin(wir[j][0]);
      wiz[j][0] = ldw(dWih + (size_t)mz * 32 + quad * 8); pin(wiz[j][0]);
      win[j][0] = ldw(dWih + (size_t)mn * 32 + quad * 8); pin(win[j][0]);
      bsr[j] = dbih[mr] + dbhh[mr];
      bsz[j] = dbih[mz] + dbhh[mz];
      bin_[j] = dbih[mn];
      bhn[j] = dbhh[mn];
      const int ml = (c & 7) * 16 + col16;
      hb0[j] = (c < 8) ? thb0[ml] : clb0[ml];
    }
    const bool w1th = (col16 < 2);
    const bool w1cl = (col16 >= 2 && col16 < FOUTC);
    const float b1v = w1th ? thb1[col16] : (w1cl ? clb1[col16 - 2] : 0.f);

    // stage u_0 (src_t = 0): 512 elems, 2 per thread
#pragma unroll
    for (int s = 0; s < 2; ++s) {
      const int i = tid + 256 * s;
      const int rr = i >> 5, cc = i & 31;
      const size_t yb = (size_t)(n0 + rr) * (LY + 1);
      const float v = (cc < FT) ? yt[yb * FT + cc] : pp[yb * FOUTC + (cc - FT)];
      uls[0][rr * UST2 + cc] = f2bf(v);
    }
    __syncthreads();  // slab + u_0 visible

#pragma unroll 1
    for (int t = 0; t < LY; ++t) {
      float un[2];
#pragma unroll
      for (int s = 0; s < 2; ++s) {
        un[s] = 0.f;
        if (t + 1 < LY) {
          const int i = tid + 256 * s;
          const int rr = i >> 5, cc = i & 31;
          const size_t yb = (size_t)(n0 + rr) * (LY + 1) + t;
          un[s] = (cc < FT) ? yt[yb * FT + cc] : pp[yb * FOUTC + (cc - FT)];
        }
      }
      const v8bf ua = ld8(uls[t & 1] + col16 * UST2 + quad * 8);
      const u16* hb = hls[t & 1] + col16 * HSTR + quad * 8;
      v8bf a[8];
#pragma unroll
      for (int k = 0; k < 8; ++k) a[k] = ld8(hb + k * 32);

      float zg[4][4];
#pragma unroll
      for (int j = 0; j < 4; ++j) {  // z first (register operands)
        v4f acc = {0.f, 0.f, 0.f, 0.f};
#pragma unroll
        for (int k = 0; k < 8; ++k) acc = mfma16(a[k], asbf(wz[j][k]), acc);
        acc = mfma16(ua, asbf(wiz[j][0]), acc);
#pragma unroll
        for (int r = 0; r < 4; ++r) zg[j][r] = sigm(acc[r] + bsz[j]);
      }
      v4f anh[4], ani[4];
#pragma unroll
      for (int j = 0; j < 4; ++j) {
        v4f ah = {0.f, 0.f, 0.f, 0.f};
#pragma unroll
        for (int k = 0; k < 8; ++k) ah = mfma16(a[k], asbf(wn[j][k]), ah);
        anh[j] = ah;
        v4f ai = {0.f, 0.f, 0.f, 0.f};
        ai = mfma16(ua, asbf(win[j][0]), ai);
        ani[j] = ai;
      }
#pragma unroll
      for (int j = 0; j < 4; ++j) {  // r from slab + fused combine
        const int c = wave + 4 * j;
        const u16* sp = slab + (c * 16 + col16) * SSTR + quad * 8;
        v4f acc = {0.f, 0.f, 0.f, 0.f};
#pragma unroll
        for (int k = 0; k < 8; ++k) acc = mfma16(a[k], ld8(sp + k * 32), acc);
        acc = mfma16(ua, asbf(wir[j][0]), acc);
#pragma unroll
        for (int r = 0; r < 4; ++r) {
          const float rg = sigm(acc[r] + bsr[j]);
          const float ng = tanh_(ani[j][r] + bin_[j] + rg * (anh[j][r] + bhn[j]));
          hreg[j][r] = (1.f - zg[j][r]) * ng + zg[j][r] * hreg[j][r];
        }
        const int cidx = c * 16 + col16;
#pragma unroll
        for (int r = 0; r < 4; ++r)
          hls[(t + 1) & 1][(quad * 4 + r) * HSTR + cidx] = f2bf(hreg[j][r]);
      }
      if (t + 1 < LY) {
#pragma unroll
        for (int s = 0; s < 2; ++s) {
          const int i = tid + 256 * s;
          uls[(t + 1) & 1][(i >> 5) * UST2 + (i & 31)] = f2bf(un[s]);
        }
      }
      __syncthreads();  // Ba: h2 + u_{t+1} visible

      // head GEMM1: W0 L2 loads issued BEFORE the h2 LDS reads
      {
        v8bf wb[2][8];
#pragma unroll
        for (int jj = 0; jj < 2; ++jj) {
          const int c = wave + 4 * (jj * 2);  // tiles j=0,2 prefetch; j=1,3 inline
          (void)c;
        }
        const u16* h2b = hls[(t + 1) & 1] + col16 * HSTR + quad * 8;
        // issue all 4 tiles' W0 loads first
        v8bf w0f[4][8];
#pragma unroll
        for (int j = 0; j < 4; ++j) {
          const int c = wave + 4 * j;
          const u16* W0 = (c < 8) ? thW0 : clW0;
          const u16* pw = W0 + (size_t)((c & 7) * 16 + col16) * HID + quad * 8;
#pragma unroll
          for (int k = 0; k < 8; ++k) w0f[j][k] = ld8(pw + k * 32);
        }
        v8bf ah2[8];
#pragma unroll
        for (int k = 0; k < 8; ++k) ah2[k] = ld8(h2b + k * 32);
#pragma unroll
        for (int j = 0; j < 4; ++j) {
          const int c = wave + 4 * j;
          v4f acc = {0.f, 0.f, 0.f, 0.f};
#pragma unroll
          for (int k = 0; k < 8; ++k) acc = mfma16(ah2[k], w0f[j][k], acc);
#pragma unroll
          for (int r = 0; r < 4; ++r)
            a1buf[(quad * 4 + r) * A1STR + c * 16 + col16] =
                f2bf(smelu_(acc[r] + hb0[j]));
        }
        (void)wb;
      }
      __syncthreads();  // Bb: a1 visible

      // head GEMM2 (wave 0): K=256 pass, block-diag B = thW1 (+) clW1
      if (wave == 0) {
        const u16* arow = a1buf + col16 * A1STR + quad * 8;
        v4f acc = {0.f, 0.f, 0.f, 0.f};
#pragma unroll
        for (int kt = 0; kt < 8; ++kt) {
          v8bf b;
#pragma unroll
          for (int j = 0; j < 8; ++j) b[j] = (__bf16)0.0f;
          if (kt < 4) {
            if (w1th) b = ld8(thW1 + col16 * 128 + kt * 32 + quad * 8);
          } else {
            if (w1cl) b = ld8(clW1 + (col16 - 2) * 128 + (kt - 4) * 32 + quad * 8);
          }
          acc = mfma16(ld8(arow + kt * 32), b, acc);
        }
        if (col16 < FOUTC) {
#pragma unroll
          for (int r = 0; r < 4; ++r)
            outp[((size_t)(n0 + quad * 4 + r) * LY + t) * FOUTC + col16] =
                acc[r] + b1v;
        }
      }
      // wave0's a1 reads precede the next a1 write (behind Ba(t+1)+GEMM1).
    }
  }
}

extern "C" void kernel_launch(void* const* d_in, const int* in_sizes, int n_in,
                              void* d_out, int out_size, void* d_ws, size_t ws_size,
                              hipStream_t stream) {
  (void)in_sizes; (void)n_in; (void)ws_size; (void)out_size;
  const float* xf   = (const float*)d_in[0];
  // d_in[1] = x : unused by forward
  const float* yt   = (const float*)d_in[2];
  const float* pp   = (const float*)d_in[3];
  const float* eWih = (const float*)d_in[4];
  const float* eWhh = (const float*)d_in[5];
  const float* ebih = (const float*)d_in[6];
  const float* ebhh = (const float*)d_in[7];
  const float* dWih = (const float*)d_in[8];
  const float* dWhh = (const float*)d_in[9];
  const float* dbih = (const float*)d_in[10];
  const float* dbhh = (const float*)d_in[11];
  const float* thW0 = (const float*)d_in[12];
  const float* thb0 = (const float*)d_in[13];
  const float* thW1 = (const float*)d_in[14];
  const float* thb1 = (const float*)d_in[15];
  const float* clW0 = (const float*)d_in[16];
  const float* clb0 = (const float*)d_in[17];
  const float* clW1 = (const float*)d_in[18];
  const float* clb1 = (const float*)d_in[19];
  float* outp = (float*)d_out;
  u16* ws = (u16*)d_ws;  // needs W_TOTAL*2 ~= 1.04 MB of scratch

  cvt_weights<<<dim3((W_TOTAL + 255) / 256), dim3(256), 0, stream>>>(
      eWih, eWhh, dWih, dWhh, thW0, thW1, clW0, clW1, ws);
  encdec_kernel<<<dim3(128), dim3(256), 0, stream>>>(
      xf, yt, pp, ebih, ebhh, dbih, dbhh, thb0, thb1, clb0, clb1, ws, outp);
}

// Round 8
// 1464.386 us; speedup vs baseline: 1.7456x; 1.0071x over previous
//
#include <hip/hip_runtime.h>

typedef __bf16 v8bf __attribute__((ext_vector_type(8)));
typedef float v4f __attribute__((ext_vector_type(4)));
typedef float v4ff __attribute__((ext_vector_type(4)));
typedef unsigned short u16;
typedef unsigned int u32;

#define DEVI __device__ __forceinline__

constexpr int LX = 168, FF = 64;
constexpr int LY = 72, FT = 22, FOUTC = 10;
constexpr int HID = 256;
constexpr int HSTR = 264;   // u16/row h tiles (528B = 33*16)
constexpr int UST2 = 40;
constexpr int A1STR = 264;
constexpr int SSTR = 264;   // slab row stride (r-gate Whh rows 0..255)

// bf16 weight cache layout in d_ws (u16 element offsets; all 16B-aligned)
constexpr int W_EWIH = 0;                      // 768*64
constexpr int W_EWHH = 49152;                  // 768*256
constexpr int W_DWIH = 245760;                 // 768*32
constexpr int W_DWHH = 270336;                 // 768*256
constexpr int W_THW0 = 466944;                 // 128*256
constexpr int W_THW1 = 499712;                 // 2*128
constexpr int W_CLW0 = 499968;                 // 128*256
constexpr int W_CLW1 = 532736;                 // 8*128
constexpr int W_TOTAL = 533760;

DEVI u16 f2bf(float f) {
  u32 x; __builtin_memcpy(&x, &f, 4);
  return (u16)((x + 0x7FFFu + ((x >> 16) & 1u)) >> 16);  // RNE (h feeds recurrence)
}
DEVI float sigm(float x) { return __builtin_amdgcn_rcpf(1.f + __expf(-x)); }
DEVI float tanh_(float x) {
  float e = __expf(-2.f * fabsf(x));
  return copysignf((1.f - e) * __builtin_amdgcn_rcpf(1.f + e), x);
}
DEVI float smelu_(float x) {
  if (x >= 1.1f) return x;
  if (x <= -1.1f) return 0.f;
  float u = x + 1.1f;
  return u * u * (1.f / 4.4f);
}
DEVI v8bf ld8(const u16* p) { return *reinterpret_cast<const v8bf*>(p); }
DEVI v4f ldw(const u16* p) { return *reinterpret_cast<const v4f*>(p); }
DEVI v8bf asbf(v4f x) { return __builtin_bit_cast(v8bf, x); }
DEVI void pin(v4f& x) { asm("" : "+v"(x)); }       // defeat rematerialization
DEVI void pinf(v4ff& x) { asm("" : "+v"(x)); }
DEVI v4f mfma16(v8bf a, v8bf b, v4f c) {
  return __builtin_amdgcn_mfma_f32_16x16x32_bf16(a, b, c, 0, 0, 0);
}
DEVI v8bf cvt2f(v4ff lo, v4ff hi) {
  v8bf r;
#pragma unroll
  for (int j = 0; j < 4; ++j) { r[j] = (__bf16)lo[j]; r[4 + j] = (__bf16)hi[j]; }
  return r;
}

// ---- prologue: convert all weight matrices f32 -> bf16 into d_ws ----
__global__ void cvt_weights(const float* __restrict__ eWih, const float* __restrict__ eWhh,
                            const float* __restrict__ dWih, const float* __restrict__ dWhh,
                            const float* __restrict__ thW0, const float* __restrict__ thW1,
                            const float* __restrict__ clW0, const float* __restrict__ clW1,
                            u16* __restrict__ ws) {
  const int i = blockIdx.x * 256 + threadIdx.x;
  if (i >= W_TOTAL) return;
  const float* src; int off;
  if      (i < W_EWHH) { src = eWih; off = W_EWIH; }
  else if (i < W_DWIH) { src = eWhh; off = W_EWHH; }
  else if (i < W_DWHH) { src = dWih; off = W_DWIH; }
  else if (i < W_THW0) { src = dWhh; off = W_DWHH; }
  else if (i < W_THW1) { src = thW0; off = W_THW0; }
  else if (i < W_CLW0) { src = thW1; off = W_THW1; }
  else if (i < W_CLW1) { src = clW0; off = W_CLW0; }
  else                 { src = clW1; off = W_CLW1; }
  ws[i] = f2bf(src[i - off]);
}

// 512 threads = 8 waves = 2 waves/SIMD: sibling wave hides the other's stalls
// (r7 post-mortem: 1 wave/SIMD left ~79% of cycles as unhidden latency).
// Wave w owns col-tiles c = w and w+8 for each gate (6 gate-tiles/wave).
__global__ __launch_bounds__(512, 2) void encdec_kernel(
    const float* __restrict__ xf, const float* __restrict__ yt, const float* __restrict__ pp,
    const float* __restrict__ ebih, const float* __restrict__ ebhh,
    const float* __restrict__ dbih, const float* __restrict__ dbhh,
    const float* __restrict__ thb0, const float* __restrict__ thb1,
    const float* __restrict__ clb0, const float* __restrict__ clb1,
    const u16* __restrict__ ws, float* __restrict__ outp) {
  __shared__ __align__(16) u16 slab[256 * SSTR];   // r-gate Whh rows (132 KB)
  __shared__ __align__(16) u16 hls[2][16 * HSTR];
  __shared__ __align__(16) u16 uls[2][16 * UST2];
  __shared__ __align__(16) u16 a1buf[16 * A1STR];

  const u16* eWih = ws + W_EWIH;
  const u16* eWhh = ws + W_EWHH;
  const u16* dWih = ws + W_DWIH;
  const u16* dWhh = ws + W_DWHH;
  const u16* thW0 = ws + W_THW0;
  const u16* thW1 = ws + W_THW1;
  const u16* clW0 = ws + W_CLW0;
  const u16* clW1 = ws + W_CLW1;

  const int tid = threadIdx.x;
  const int wave = tid >> 6;        // 8 waves
  const int lane = tid & 63;
  const int col16 = lane & 15;
  const int quad = lane >> 4;
  const int n0 = blockIdx.x * 16;

  for (int i = tid; i < 16 * HSTR; i += 512) hls[0][i] = 0;

  float hreg[2][4];
#pragma unroll
  for (int j = 0; j < 2; ++j)
#pragma unroll
    for (int r = 0; r < 4; ++r) hreg[j][r] = 0.f;

  // Persistent (laundered): z,n Whh = 128 regs; encoder z Wih = 16.
  v4f wz[2][8], wn[2][8];
  v4f wiz[2][2];
  float bsr[2], bsz[2], bin_[2], bhn[2];

  // ================= encoder phase =================
  {
    for (int i = tid; i < 256 * 32; i += 512) {  // stage r-gate Whh slab
      const int row = i >> 5, kb = (i & 31) << 3;
      *reinterpret_cast<v8bf*>(&slab[row * SSTR + kb]) = ld8(eWhh + row * HID + kb);
    }
#pragma unroll
    for (int j = 0; j < 2; ++j) {
      const int c = wave + 8 * j;
      const int mr = c * 16 + col16, mz = 256 + mr, mn = 512 + mr;
#pragma unroll
      for (int k = 0; k < 8; ++k) {
        wz[j][k] = ldw(eWhh + (size_t)mz * HID + k * 32 + quad * 8); pin(wz[j][k]);
        wn[j][k] = ldw(eWhh + (size_t)mn * HID + k * 32 + quad * 8); pin(wn[j][k]);
      }
      wiz[j][0] = ldw(eWih + (size_t)mz * FF + quad * 8);      pin(wiz[j][0]);
      wiz[j][1] = ldw(eWih + (size_t)mz * FF + 32 + quad * 8); pin(wiz[j][1]);
      bsr[j] = ebih[mr] + ebhh[mr];
      bsz[j] = ebih[mz] + ebhh[mz];
      bin_[j] = ebih[mn];
      bhn[j] = ebhh[mn];
    }
    const float* xbase = xf + (size_t)(n0 + col16) * LX * FF + quad * 8;
    v4ff xr0 = *(const v4ff*)(xbase);
    v4ff xr1 = *(const v4ff*)(xbase + 4);
    v4ff xr2 = *(const v4ff*)(xbase + 32);
    v4ff xr3 = *(const v4ff*)(xbase + 36);
    __syncthreads();  // slab + h-init visible

#pragma unroll 1
    for (int t = 0; t < LX; ++t) {
      v4ff xn0, xn1, xn2, xn3;
      if (t + 1 < LX) {  // prefetch next x across this step
        const float* xn = xbase + (size_t)(t + 1) * FF;
        xn0 = *(const v4ff*)(xn);      pinf(xn0);
        xn1 = *(const v4ff*)(xn + 4);  pinf(xn1);
        xn2 = *(const v4ff*)(xn + 32); pinf(xn2);
        xn3 = *(const v4ff*)(xn + 36); pinf(xn3);
      }
      const u16* hb = hls[t & 1] + col16 * HSTR + quad * 8;
      v8bf a[8];
#pragma unroll
      for (int k = 0; k < 8; ++k) a[k] = ld8(hb + k * 32);
      const v8bf xa0 = cvt2f(xr0, xr1);
      const v8bf xa1 = cvt2f(xr2, xr3);

      // z first: pure register operands (slab ds_reads land underneath)
      float zg[2][4];
#pragma unroll
      for (int j = 0; j < 2; ++j) {
        v4f acc = {0.f, 0.f, 0.f, 0.f};
#pragma unroll
        for (int k = 0; k < 8; ++k) acc = mfma16(a[k], asbf(wz[j][k]), acc);
        acc = mfma16(xa0, asbf(wiz[j][0]), acc);
        acc = mfma16(xa1, asbf(wiz[j][1]), acc);
#pragma unroll
        for (int r = 0; r < 4; ++r) zg[j][r] = sigm(acc[r] + bsz[j]);
      }
      // r second: slab B-frags + streamed Wih (JIT; sibling wave hides L2)
      float rg[2][4];
#pragma unroll
      for (int j = 0; j < 2; ++j) {
        const int c = wave + 8 * j;
        const u16* pw = eWih + (size_t)(c * 16 + col16) * FF + quad * 8;
        const v8bf wir0 = ld8(pw), wir1 = ld8(pw + 32);
        const u16* sp = slab + (c * 16 + col16) * SSTR + quad * 8;
        v4f acc = {0.f, 0.f, 0.f, 0.f};
#pragma unroll
        for (int k = 0; k < 8; ++k) acc = mfma16(a[k], ld8(sp + k * 32), acc);
        acc = mfma16(xa0, wir0, acc);
        acc = mfma16(xa1, wir1, acc);
#pragma unroll
        for (int r = 0; r < 4; ++r) rg[j][r] = sigm(acc[r] + bsr[j]);
      }
      // n last: persistent Whh, streamed Wih, fused combine (no anh/ani bufs)
#pragma unroll
      for (int j = 0; j < 2; ++j) {
        const int c = wave + 8 * j;
        const u16* pw = eWih + (size_t)(512 + c * 16 + col16) * FF + quad * 8;
        const v8bf win0 = ld8(pw), win1 = ld8(pw + 32);
        v4f ah = {0.f, 0.f, 0.f, 0.f};
#pragma unroll
        for (int k = 0; k < 8; ++k) ah = mfma16(a[k], asbf(wn[j][k]), ah);
        v4f ai = {0.f, 0.f, 0.f, 0.f};
        ai = mfma16(xa0, win0, ai);
        ai = mfma16(xa1, win1, ai);
        const int cidx = c * 16 + col16;
#pragma unroll
        for (int r = 0; r < 4; ++r) {
          const float ng = tanh_(ai[r] + bin_[j] + rg[j][r] * (ah[r] + bhn[j]));
          hreg[j][r] = (1.f - zg[j][r]) * ng + zg[j][r] * hreg[j][r];
          hls[(t + 1) & 1][(quad * 4 + r) * HSTR + cidx] = f2bf(hreg[j][r]);
        }
      }
      __syncthreads();
      xr0 = xn0; xr1 = xn1; xr2 = xn2; xr3 = xn3;
    }
  }
  // h_enc in hls[LX & 1] == hls[0]

  // ================= decoder phase =================
  {
    for (int i = tid; i < 256 * 32; i += 512) {  // restage slab with dWhh r rows
      const int row = i >> 5, kb = (i & 31) << 3;
      *reinterpret_cast<v8bf*>(&slab[row * SSTR + kb]) = ld8(dWhh + row * HID + kb);
    }
    float hb0[2];
#pragma unroll
    for (int j = 0; j < 2; ++j) {
      const int c = wave + 8 * j;
      const int mr = c * 16 + col16, mz = 256 + mr, mn = 512 + mr;
#pragma unroll
      for (int k = 0; k < 8; ++k) {
        wz[j][k] = ldw(dWhh + (size_t)mz * HID + k * 32 + quad * 8); pin(wz[j][k]);
        wn[j][k] = ldw(dWhh + (size_t)mn * HID + k * 32 + quad * 8); pin(wn[j][k]);
      }
      wiz[j][0] = ldw(dWih + (size_t)mz * 32 + quad * 8); pin(wiz[j][0]);
      bsr[j] = dbih[mr] + dbhh[mr];
      bsz[j] = dbih[mz] + dbhh[mz];
      bin_[j] = dbih[mn];
      bhn[j] = dbhh[mn];
      const int ml = wave * 16 + col16;
      hb0[j] = (j == 0) ? thb0[ml] : clb0[ml];
    }
    const bool w1th = (col16 < 2);
    const bool w1cl = (col16 >= 2 && col16 < FOUTC);
    const float b1v = w1th ? thb1[col16] : (w1cl ? clb1[col16 - 2] : 0.f);

    // stage u_0 (src_t = 0): 512 elems, 1 per thread
    {
      const int rr = tid >> 5, cc = tid & 31;
      const size_t yb = (size_t)(n0 + rr) * (LY + 1);
      const float v = (cc < FT) ? yt[yb * FT + cc] : pp[yb * FOUTC + (cc - FT)];
      uls[0][rr * UST2 + cc] = f2bf(v);
    }
    __syncthreads();  // slab + u_0 visible

    const int srr = tid >> 5, scc = tid & 31;
    const size_t ybase = (size_t)(n0 + srr) * (LY + 1);

#pragma unroll 1
    for (int t = 0; t < LY; ++t) {
      float un = 0.f;
      if (t + 1 < LY)
        un = (scc < FT) ? yt[(ybase + t) * FT + scc]
                        : pp[(ybase + t) * FOUTC + (scc - FT)];
      const v8bf ua = ld8(uls[t & 1] + col16 * UST2 + quad * 8);
      const u16* hb = hls[t & 1] + col16 * HSTR + quad * 8;
      v8bf a[8];
#pragma unroll
      for (int k = 0; k < 8; ++k) a[k] = ld8(hb + k * 32);

      float zg[2][4];
#pragma unroll
      for (int j = 0; j < 2; ++j) {  // z first (register operands)
        v4f acc = {0.f, 0.f, 0.f, 0.f};
#pragma unroll
        for (int k = 0; k < 8; ++k) acc = mfma16(a[k], asbf(wz[j][k]), acc);
        acc = mfma16(ua, asbf(wiz[j][0]), acc);
#pragma unroll
        for (int r = 0; r < 4; ++r) zg[j][r] = sigm(acc[r] + bsz[j]);
      }
      float rg[2][4];
#pragma unroll
      for (int j = 0; j < 2; ++j) {  // r from slab + streamed Wih
        const int c = wave + 8 * j;
        const v8bf wir0 = ld8(dWih + (size_t)(c * 16 + col16) * 32 + quad * 8);
        const u16* sp = slab + (c * 16 + col16) * SSTR + quad * 8;
        v4f acc = {0.f, 0.f, 0.f, 0.f};
#pragma unroll
        for (int k = 0; k < 8; ++k) acc = mfma16(a[k], ld8(sp + k * 32), acc);
        acc = mfma16(ua, wir0, acc);
#pragma unroll
        for (int r = 0; r < 4; ++r) rg[j][r] = sigm(acc[r] + bsr[j]);
      }
#pragma unroll
      for (int j = 0; j < 2; ++j) {  // n last, fused combine
        const int c = wave + 8 * j;
        const v8bf win0 = ld8(dWih + (size_t)(512 + c * 16 + col16) * 32 + quad * 8);
        v4f ah = {0.f, 0.f, 0.f, 0.f};
#pragma unroll
        for (int k = 0; k < 8; ++k) ah = mfma16(a[k], asbf(wn[j][k]), ah);
        v4f ai = {0.f, 0.f, 0.f, 0.f};
        ai = mfma16(ua, win0, ai);
        const int cidx = c * 16 + col16;
#pragma unroll
        for (int r = 0; r < 4; ++r) {
          const float ng = tanh_(ai[r] + bin_[j] + rg[j][r] * (ah[r] + bhn[j]));
          hreg[j][r] = (1.f - zg[j][r]) * ng + zg[j][r] * hreg[j][r];
          hls[(t + 1) & 1][(quad * 4 + r) * HSTR + cidx] = f2bf(hreg[j][r]);
        }
      }
      if (t + 1 < LY) uls[(t + 1) & 1][srr * UST2 + scc] = f2bf(un);
      __syncthreads();  // Ba: h2 + u_{t+1} visible

      // head GEMM1: 2 tiles/wave (j=0: temphr tile `wave`, j=1: class tile)
      {
        v8bf w0f[2][8];
        const u16* pw0 = thW0 + (size_t)(wave * 16 + col16) * HID + quad * 8;
        const u16* pw1 = clW0 + (size_t)(wave * 16 + col16) * HID + quad * 8;
#pragma unroll
        for (int k = 0; k < 8; ++k) {
          w0f[0][k] = ld8(pw0 + k * 32);
          w0f[1][k] = ld8(pw1 + k * 32);
        }
        const u16* h2b = hls[(t + 1) & 1] + col16 * HSTR + quad * 8;
        v8bf ah2[8];
#pragma unroll
        for (int k = 0; k < 8; ++k) ah2[k] = ld8(h2b + k * 32);
#pragma unroll
        for (int j = 0; j < 2; ++j) {
          const int c = wave + 8 * j;
          v4f acc = {0.f, 0.f, 0.f, 0.f};
#pragma unroll
          for (int k = 0; k < 8; ++k) acc = mfma16(ah2[k], w0f[j][k], acc);
#pragma unroll
          for (int r = 0; r < 4; ++r)
            a1buf[(quad * 4 + r) * A1STR + c * 16 + col16] =
                f2bf(smelu_(acc[r] + hb0[j]));
        }
      }
      __syncthreads();  // Bb: a1 visible

      // head GEMM2 (wave 0): K=256 pass, block-diag B = thW1 (+) clW1
      if (wave == 0) {
        const u16* arow = a1buf + col16 * A1STR + quad * 8;
        v4f acc = {0.f, 0.f, 0.f, 0.f};
#pragma unroll
        for (int kt = 0; kt < 8; ++kt) {
          v8bf b;
#pragma unroll
          for (int j = 0; j < 8; ++j) b[j] = (__bf16)0.0f;
          if (kt < 4) {
            if (w1th) b = ld8(thW1 + col16 * 128 + kt * 32 + quad * 8);
          } else {
            if (w1cl) b = ld8(clW1 + (col16 - 2) * 128 + (kt - 4) * 32 + quad * 8);
          }
          acc = mfma16(ld8(arow + kt * 32), b, acc);
        }
        if (col16 < FOUTC) {
#pragma unroll
          for (int r = 0; r < 4; ++r)
            outp[((size_t)(n0 + quad * 4 + r) * LY + t) * FOUTC + col16] =
                acc[r] + b1v;
        }
      }
      // wave0's a1 reads precede the next a1 write (behind Ba(t+1)+GEMM1).
    }
  }
}

extern "C" void kernel_launch(void* const* d_in, const int* in_sizes, int n_in,
                              void* d_out, int out_size, void* d_ws, size_t ws_size,
                              hipStream_t stream) {
  (void)in_sizes; (void)n_in; (void)ws_size; (void)out_size;
  const float* xf   = (const float*)d_in[0];
  // d_in[1] = x : unused by forward
  const float* yt   = (const float*)d_in[2];
  const float* pp   = (const float*)d_in[3];
  const float* eWih = (const float*)d_in[4];
  const float* eWhh = (const float*)d_in[5];
  const float* ebih = (const float*)d_in[6];
  const float* ebhh = (const float*)d_in[7];
  const float* dWih = (const float*)d_in[8];
  const float* dWhh = (const float*)d_in[9];
  const float* dbih = (const float*)d_in[10];
  const float* dbhh = (const float*)d_in[11];
  const float* thW0 = (const float*)d_in[12];
  const float* thb0 = (const float*)d_in[13];
  const float* thW1 = (const float*)d_in[14];
  const float* thb1 = (const float*)d_in[15];
  const float* clW0 = (const float*)d_in[16];
  const float* clb0 = (const float*)d_in[17];
  const float* clW1 = (const float*)d_in[18];
  const float* clb1 = (const float*)d_in[19];
  float* outp = (float*)d_out;
  u16* ws = (u16*)d_ws;  // needs W_TOTAL*2 ~= 1.04 MB of scratch

  cvt_weights<<<dim3((W_TOTAL + 255) / 256), dim3(256), 0, stream>>>(
      eWih, eWhh, dWih, dWhh, thW0, thW1, clW0, clW1, ws);
  encdec_kernel<<<dim3(128), dim3(512), 0, stream>>>(
      xf, yt, pp, ebih, ebhh, dbih, dbhh, thb0, thb1, clb0, clb1, ws, outp);
}

// Round 10
// 1179.026 us; speedup vs baseline: 2.1681x; 1.2420x over previous
//
#include <hip/hip_runtime.h>

typedef __bf16 v8bf __attribute__((ext_vector_type(8)));
typedef float v4f __attribute__((ext_vector_type(4)));
typedef float v4ff __attribute__((ext_vector_type(4)));
typedef unsigned short u16;
typedef unsigned int u32;

#define DEVI __device__ __forceinline__

constexpr int LX = 168, FF = 64;
constexpr int LY = 72, FT = 22, FOUTC = 10;
constexpr int HID = 256;
constexpr int HSTR = 264;   // u16/row for 16x256 tiles (528B = 33*16)
constexpr int UST2 = 40;
constexpr int SSTR = 264;   // slab row stride (r-gate Whh rows 0..255)

// bf16 weight cache layout in d_ws (u16 element offsets; all 16B-aligned)
constexpr int W_EWIH = 0;                      // 768*64
constexpr int W_EWHH = 49152;                  // 768*256
constexpr int W_DWIH = 245760;                 // 768*32
constexpr int W_DWHH = 270336;                 // 768*256
constexpr int W_THW0 = 466944;                 // 128*256
constexpr int W_THW1 = 499712;                 // 2*128
constexpr int W_CLW0 = 499968;                 // 128*256
constexpr int W_CLW1 = 532736;                 // 8*128
constexpr int W_TOTAL = 533760;

DEVI u16 f2bf(float f) {
  u32 x; __builtin_memcpy(&x, &f, 4);
  return (u16)((x + 0x7FFFu + ((x >> 16) & 1u)) >> 16);  // RNE (h feeds recurrence)
}
DEVI float sigm(float x) { return __builtin_amdgcn_rcpf(1.f + __expf(-x)); }
DEVI float tanh_(float x) {
  float e = __expf(-2.f * fabsf(x));
  return copysignf((1.f - e) * __builtin_amdgcn_rcpf(1.f + e), x);
}
DEVI float smelu_(float x) {
  if (x >= 1.1f) return x;
  if (x <= -1.1f) return 0.f;
  float u = x + 1.1f;
  return u * u * (1.f / 4.4f);
}
DEVI v8bf ld8(const u16* p) { return *reinterpret_cast<const v8bf*>(p); }
DEVI v4f ldw(const u16* p) { return *reinterpret_cast<const v4f*>(p); }
DEVI v8bf asbf(v4f x) { return __builtin_bit_cast(v8bf, x); }
DEVI void pin(v4f& x) { asm("" : "+v"(x)); }       // defeat rematerialization
DEVI v4f mfma16(v8bf a, v8bf b, v4f c) {
  return __builtin_amdgcn_mfma_f32_16x16x32_bf16(a, b, c, 0, 0, 0);
}
DEVI v8bf cvt2f(v4ff lo, v4ff hi) {
  v8bf r;
#pragma unroll
  for (int j = 0; j < 4; ++j) { r[j] = (__bf16)lo[j]; r[4 + j] = (__bf16)hi[j]; }
  return r;
}

// ---- prologue: convert all weight matrices f32 -> bf16 into d_ws ----
__global__ void cvt_weights(const float* __restrict__ eWih, const float* __restrict__ eWhh,
                            const float* __restrict__ dWih, const float* __restrict__ dWhh,
                            const float* __restrict__ thW0, const float* __restrict__ thW1,
                            const float* __restrict__ clW0, const float* __restrict__ clW1,
                            u16* __restrict__ ws) {
  const int i = blockIdx.x * 256 + threadIdx.x;
  if (i >= W_TOTAL) return;
  const float* src; int off;
  if      (i < W_EWHH) { src = eWih; off = W_EWIH; }
  else if (i < W_DWIH) { src = eWhh; off = W_EWHH; }
  else if (i < W_DWHH) { src = dWih; off = W_DWIH; }
  else if (i < W_THW0) { src = dWhh; off = W_DWHH; }
  else if (i < W_THW1) { src = thW0; off = W_THW0; }
  else if (i < W_CLW0) { src = thW1; off = W_THW1; }
  else if (i < W_CLW1) { src = clW0; off = W_CLW0; }
  else                 { src = clW1; off = W_CLW1; }
  ws[i] = f2bf(src[i - off]);
}

// 512 threads = 8 waves; wave w owns gate col-tiles c = w, w+8.
// Encoder: double-h, 1 barrier/step, 6 interleaved MFMA chains (k-outer).
// Decoder: single-h in hls[0] (2 barriers/step); a1 double-buffered as
// {hls[1], a1x}; GEMM1(t-1) reuses a[]=h_t; GEMM2(t-2) by wave0 inside the
// work phase. (r9 bug: A1STR=136 < 256 cols -> row overlap; fixed by 264
// strides + buffer aliasing to fit 160 KiB.)
__global__ __launch_bounds__(512, 2) void encdec_kernel(
    const float* __restrict__ xf, const float* __restrict__ yt, const float* __restrict__ pp,
    const float* __restrict__ ebih, const float* __restrict__ ebhh,
    const float* __restrict__ dbih, const float* __restrict__ dbhh,
    const float* __restrict__ thb0, const float* __restrict__ thb1,
    const float* __restrict__ clb0, const float* __restrict__ clb1,
    const u16* __restrict__ ws, float* __restrict__ outp) {
  __shared__ __align__(16) u16 slab[256 * SSTR];   // r-gate Whh rows (132 KB)
  __shared__ __align__(16) u16 hls[2][16 * HSTR];  // enc: h dbuf; dec: h=hls[0], a1#0=hls[1]
  __shared__ __align__(16) u16 a1x[16 * HSTR];     // a1 buffer #1
  __shared__ __align__(16) u16 uls[2][16 * UST2];

  const u16* eWih = ws + W_EWIH;
  const u16* eWhh = ws + W_EWHH;
  const u16* dWih = ws + W_DWIH;
  const u16* dWhh = ws + W_DWHH;
  const u16* thW0 = ws + W_THW0;
  const u16* thW1 = ws + W_THW1;
  const u16* clW0 = ws + W_CLW0;
  const u16* clW1 = ws + W_CLW1;

  const int tid = threadIdx.x;
  const int wave = tid >> 6;        // 8 waves
  const int lane = tid & 63;
  const int col16 = lane & 15;
  const int quad = lane >> 4;
  const int n0 = blockIdx.x * 16;

  for (int i = tid; i < 16 * HSTR; i += 512) hls[0][i] = 0;

  float hreg[2][4];
#pragma unroll
  for (int j = 0; j < 2; ++j)
#pragma unroll
    for (int r = 0; r < 4; ++r) hreg[j][r] = 0.f;

  // Persistent (laundered -> AGPR): z,n Whh fragments (128 regs).
  v4f wz[2][8], wn[2][8];
  float bsr[2], bsz[2], bin_[2], bhn[2];

  // ================= encoder phase =================
  {
    for (int i = tid; i < 256 * 32; i += 512) {  // stage r-gate Whh slab
      const int row = i >> 5, kb = (i & 31) << 3;
      *reinterpret_cast<v8bf*>(&slab[row * SSTR + kb]) = ld8(eWhh + row * HID + kb);
    }
#pragma unroll
    for (int j = 0; j < 2; ++j) {
      const int c = wave + 8 * j;
      const int mr = c * 16 + col16, mz = 256 + mr, mn = 512 + mr;
#pragma unroll
      for (int k = 0; k < 8; ++k) {
        wz[j][k] = ldw(eWhh + (size_t)mz * HID + k * 32 + quad * 8); pin(wz[j][k]);
        wn[j][k] = ldw(eWhh + (size_t)mn * HID + k * 32 + quad * 8); pin(wn[j][k]);
      }
      bsr[j] = ebih[mr] + ebhh[mr];
      bsz[j] = ebih[mz] + ebhh[mz];
      bin_[j] = ebih[mn];
      bhn[j] = ebhh[mn];
    }
    const float* xbase = xf + (size_t)(n0 + col16) * LX * FF + quad * 8;
    const u16* sp0 = slab + (wave * 16 + col16) * SSTR + quad * 8;
    const u16* sp1 = slab + ((wave + 8) * 16 + col16) * SSTR + quad * 8;
    __syncthreads();  // slab + h-init visible

#pragma unroll 1
    for (int t = 0; t < LX; ++t) {
      const float* xr = xbase + (size_t)t * FF;
      const v4ff x0 = *(const v4ff*)(xr);
      const v4ff x1 = *(const v4ff*)(xr + 4);
      const v4ff x2 = *(const v4ff*)(xr + 32);
      const v4ff x3 = *(const v4ff*)(xr + 36);
      const u16* hb = hls[t & 1] + col16 * HSTR + quad * 8;
      v8bf a[8];
#pragma unroll
      for (int k = 0; k < 8; ++k) a[k] = ld8(hb + k * 32);

      // 6 independent h-chains, k-outer interleave
      v4f az[2] = {{0.f,0.f,0.f,0.f},{0.f,0.f,0.f,0.f}};
      v4f ar[2] = {{0.f,0.f,0.f,0.f},{0.f,0.f,0.f,0.f}};
      v4f an[2] = {{0.f,0.f,0.f,0.f},{0.f,0.f,0.f,0.f}};
#pragma unroll
      for (int k = 0; k < 8; ++k) {
        az[0] = mfma16(a[k], asbf(wz[0][k]), az[0]);
        az[1] = mfma16(a[k], asbf(wz[1][k]), az[1]);
        ar[0] = mfma16(a[k], ld8(sp0 + k * 32), ar[0]);
        ar[1] = mfma16(a[k], ld8(sp1 + k * 32), ar[1]);
        an[0] = mfma16(a[k], asbf(wn[0][k]), an[0]);
        an[1] = mfma16(a[k], asbf(wn[1][k]), an[1]);
      }
      const v8bf xa0 = cvt2f(x0, x1);
      const v8bf xa1 = cvt2f(x2, x3);
      v4f ai[2] = {{0.f,0.f,0.f,0.f},{0.f,0.f,0.f,0.f}};
#pragma unroll
      for (int j = 0; j < 2; ++j) {
        const int m = (wave + 8 * j) * 16 + col16;
        const u16* pwr = eWih + (size_t)m * FF + quad * 8;
        const u16* pwz = eWih + (size_t)(256 + m) * FF + quad * 8;
        const u16* pwn = eWih + (size_t)(512 + m) * FF + quad * 8;
        az[j] = mfma16(xa0, ld8(pwz), az[j]);
        az[j] = mfma16(xa1, ld8(pwz + 32), az[j]);
        ar[j] = mfma16(xa0, ld8(pwr), ar[j]);
        ar[j] = mfma16(xa1, ld8(pwr + 32), ar[j]);
        ai[j] = mfma16(xa0, ld8(pwn), ai[j]);
        ai[j] = mfma16(xa1, ld8(pwn + 32), ai[j]);
      }
#pragma unroll
      for (int j = 0; j < 2; ++j) {
        const int cidx = (wave + 8 * j) * 16 + col16;
#pragma unroll
        for (int r = 0; r < 4; ++r) {
          const float zg = sigm(az[j][r] + bsz[j]);
          const float rg = sigm(ar[j][r] + bsr[j]);
          const float ng = tanh_(ai[j][r] + bin_[j] + rg * (an[j][r] + bhn[j]));
          hreg[j][r] = (1.f - zg) * ng + zg * hreg[j][r];
          hls[(t + 1) & 1][(quad * 4 + r) * HSTR + cidx] = f2bf(hreg[j][r]);
        }
      }
      __syncthreads();
    }
  }
  // h_enc in hls[LX & 1] == hls[0]  (LX even)

  // ================= decoder phase =================
  {
    for (int i = tid; i < 256 * 32; i += 512) {  // restage slab with dWhh r rows
      const int row = i >> 5, kb = (i & 31) << 3;
      *reinterpret_cast<v8bf*>(&slab[row * SSTR + kb]) = ld8(dWhh + row * HID + kb);
    }
    float hb0[2];
#pragma unroll
    for (int j = 0; j < 2; ++j) {
      const int c = wave + 8 * j;
      const int mr = c * 16 + col16, mz = 256 + mr, mn = 512 + mr;
#pragma unroll
      for (int k = 0; k < 8; ++k) {
        wz[j][k] = ldw(dWhh + (size_t)mz * HID + k * 32 + quad * 8); pin(wz[j][k]);
        wn[j][k] = ldw(dWhh + (size_t)mn * HID + k * 32 + quad * 8); pin(wn[j][k]);
      }
      bsr[j] = dbih[mr] + dbhh[mr];
      bsz[j] = dbih[mz] + dbhh[mz];
      bin_[j] = dbih[mn];
      bhn[j] = dbhh[mn];
      const int ml = wave * 16 + col16;
      hb0[j] = (j == 0) ? thb0[ml] : clb0[ml];
    }
    const bool w1th = (col16 < 2);
    const bool w1cl = (col16 >= 2 && col16 < FOUTC);
    const float b1v = w1th ? thb1[col16] : (w1cl ? clb1[col16 - 2] : 0.f);
    const u16* sp0 = slab + (wave * 16 + col16) * SSTR + quad * 8;
    const u16* sp1 = slab + ((wave + 8) * 16 + col16) * SSTR + quad * 8;

    const int srr = tid >> 5, scc = tid & 31;
    const size_t ybase = (size_t)(n0 + srr) * (LY + 1);
    {  // stage u_0 (src_t = 0)
      const float v = (scc < FT) ? yt[ybase * FT + scc] : pp[ybase * FOUTC + (scc - FT)];
      uls[0][srr * UST2 + scc] = f2bf(v);
    }
    __syncthreads();  // slab + u_0 visible (also last h write already fenced)

#pragma unroll 1
    for (int t = 0; t < LY; ++t) {
      float un = 0.f;
      if (t + 1 < LY)
        un = (scc < FT) ? yt[(ybase + t) * FT + scc]
                        : pp[(ybase + t) * FOUTC + (scc - FT)];
      const v8bf ua = ld8(uls[t & 1] + col16 * UST2 + quad * 8);
      const u16* hb = hls[0] + col16 * HSTR + quad * 8;  // h_t (single buffer)
      v8bf a[8];
#pragma unroll
      for (int k = 0; k < 8; ++k) a[k] = ld8(hb + k * 32);
      __syncthreads();  // barR: all hls[0]/uls reads done before rewrites

      // GEMM2 for step t-2 (wave 0): reads a1 buffer written in slot t-1.
      // Next writer of this buffer is GEMM1(t) in slot t+1 (2 barriers away).
      if (wave == 0 && t >= 2) {
        const u16* arow = ((t & 1) ? a1x : hls[1]) + col16 * HSTR + quad * 8;
        v4f acc = {0.f, 0.f, 0.f, 0.f};
#pragma unroll
        for (int kt = 0; kt < 8; ++kt) {
          v8bf b;
#pragma unroll
          for (int j = 0; j < 8; ++j) b[j] = (__bf16)0.0f;
          if (kt < 4) { if (w1th) b = ld8(thW1 + col16 * 128 + kt * 32 + quad * 8); }
          else        { if (w1cl) b = ld8(clW1 + (col16 - 2) * 128 + (kt - 4) * 32 + quad * 8); }
          acc = mfma16(ld8(arow + kt * 32), b, acc);
        }
        if (col16 < FOUTC) {
#pragma unroll
          for (int r = 0; r < 4; ++r)
            outp[((size_t)(n0 + quad * 4 + r) * LY + (t - 2)) * FOUTC + col16] =
                acc[r] + b1v;
        }
      }

      // gates (6 interleaved chains)
      v4f az[2] = {{0.f,0.f,0.f,0.f},{0.f,0.f,0.f,0.f}};
      v4f ar[2] = {{0.f,0.f,0.f,0.f},{0.f,0.f,0.f,0.f}};
      v4f an[2] = {{0.f,0.f,0.f,0.f},{0.f,0.f,0.f,0.f}};
#pragma unroll
      for (int k = 0; k < 8; ++k) {
        az[0] = mfma16(a[k], asbf(wz[0][k]), az[0]);
        az[1] = mfma16(a[k], asbf(wz[1][k]), az[1]);
        ar[0] = mfma16(a[k], ld8(sp0 + k * 32), ar[0]);
        ar[1] = mfma16(a[k], ld8(sp1 + k * 32), ar[1]);
        an[0] = mfma16(a[k], asbf(wn[0][k]), an[0]);
        an[1] = mfma16(a[k], asbf(wn[1][k]), an[1]);
      }
      v4f ai[2] = {{0.f,0.f,0.f,0.f},{0.f,0.f,0.f,0.f}};
#pragma unroll
      for (int j = 0; j < 2; ++j) {
        const int m = (wave + 8 * j) * 16 + col16;
        az[j] = mfma16(ua, ld8(dWih + (size_t)(256 + m) * 32 + quad * 8), az[j]);
        ar[j] = mfma16(ua, ld8(dWih + (size_t)m * 32 + quad * 8), ar[j]);
        ai[j] = mfma16(ua, ld8(dWih + (size_t)(512 + m) * 32 + quad * 8), ai[j]);
      }
#pragma unroll
      for (int j = 0; j < 2; ++j) {
        const int cidx = (wave + 8 * j) * 16 + col16;
#pragma unroll
        for (int r = 0; r < 4; ++r) {
          const float zg = sigm(az[j][r] + bsz[j]);
          const float rg = sigm(ar[j][r] + bsr[j]);
          const float ng = tanh_(ai[j][r] + bin_[j] + rg * (an[j][r] + bhn[j]));
          hreg[j][r] = (1.f - zg) * ng + zg * hreg[j][r];
          hls[0][(quad * 4 + r) * HSTR + cidx] = f2bf(hreg[j][r]);
        }
      }

      // GEMM1 for step t-1: a[] == h_t == h2_{t-1} (zero extra LDS reads)
      if (t >= 1) {
        u16* a1w = ((t - 1) & 1) ? a1x : hls[1];
#pragma unroll
        for (int j = 0; j < 2; ++j) {
          const u16* W0 = (j == 0) ? thW0 : clW0;
          const u16* pw = W0 + (size_t)(wave * 16 + col16) * HID + quad * 8;
          v4f acc = {0.f, 0.f, 0.f, 0.f};
#pragma unroll
          for (int k = 0; k < 8; ++k) acc = mfma16(a[k], ld8(pw + k * 32), acc);
          const int c = wave + 8 * j;
#pragma unroll
          for (int r = 0; r < 4; ++r)
            a1w[(quad * 4 + r) * HSTR + c * 16 + col16] =
                f2bf(smelu_(acc[r] + hb0[j]));
        }
      }
      if (t + 1 < LY) uls[(t + 1) & 1][srr * UST2 + scc] = f2bf(un);
      __syncthreads();  // barW: h_{t+1}, u_{t+1}, a1(t-1) visible
    }

    // ---- epilogue: GEMM1(LY-1), GEMM2(LY-2), then GEMM2(LY-1) ----
    {
      const u16* h2b = hls[0] + col16 * HSTR + quad * 8;  // h_LY = h2_{LY-1}
      v8bf ah2[8];
#pragma unroll
      for (int k = 0; k < 8; ++k) ah2[k] = ld8(h2b + k * 32);
      u16* a1w = ((LY - 1) & 1) ? a1x : hls[1];           // = a1x (LY-1 odd)
#pragma unroll
      for (int j = 0; j < 2; ++j) {
        const u16* W0 = (j == 0) ? thW0 : clW0;
        const u16* pw = W0 + (size_t)(wave * 16 + col16) * HID + quad * 8;
        v4f acc = {0.f, 0.f, 0.f, 0.f};
#pragma unroll
        for (int k = 0; k < 8; ++k) acc = mfma16(ah2[k], ld8(pw + k * 32), acc);
        const int c = wave + 8 * j;
#pragma unroll
        for (int r = 0; r < 4; ++r)
          a1w[(quad * 4 + r) * HSTR + c * 16 + col16] =
              f2bf(smelu_(acc[r] + hb0[j]));
      }
      if (wave == 0) {  // GEMM2(LY-2): buffer written in slot LY-1, fenced by barW
        const u16* arow = (((LY - 2) & 1) ? a1x : hls[1]) + col16 * HSTR + quad * 8;
        v4f acc = {0.f, 0.f, 0.f, 0.f};
#pragma unroll
        for (int kt = 0; kt < 8; ++kt) {
          v8bf b;
#pragma unroll
          for (int j = 0; j < 8; ++j) b[j] = (__bf16)0.0f;
          if (kt < 4) { if (w1th) b = ld8(thW1 + col16 * 128 + kt * 32 + quad * 8); }
          else        { if (w1cl) b = ld8(clW1 + (col16 - 2) * 128 + (kt - 4) * 32 + quad * 8); }
          acc = mfma16(ld8(arow + kt * 32), b, acc);
        }
        if (col16 < FOUTC) {
#pragma unroll
          for (int r = 0; r < 4; ++r)
            outp[((size_t)(n0 + quad * 4 + r) * LY + (LY - 2)) * FOUTC + col16] =
                acc[r] + b1v;
        }
      }
      __syncthreads();
      if (wave == 0) {  // GEMM2(LY-1)
        const u16* arow = (((LY - 1) & 1) ? a1x : hls[1]) + col16 * HSTR + quad * 8;
        v4f acc = {0.f, 0.f, 0.f, 0.f};
#pragma unroll
        for (int kt = 0; kt < 8; ++kt) {
          v8bf b;
#pragma unroll
          for (int j = 0; j < 8; ++j) b[j] = (__bf16)0.0f;
          if (kt < 4) { if (w1th) b = ld8(thW1 + col16 * 128 + kt * 32 + quad * 8); }
          else        { if (w1cl) b = ld8(clW1 + (col16 - 2) * 128 + (kt - 4) * 32 + quad * 8); }
          acc = mfma16(ld8(arow + kt * 32), b, acc);
        }
        if (col16 < FOUTC) {
#pragma unroll
          for (int r = 0; r < 4; ++r)
            outp[((size_t)(n0 + quad * 4 + r) * LY + (LY - 1)) * FOUTC + col16] =
                acc[r] + b1v;
        }
      }
    }
  }
}

extern "C" void kernel_launch(void* const* d_in, const int* in_sizes, int n_in,
                              void* d_out, int out_size, void* d_ws, size_t ws_size,
                              hipStream_t stream) {
  (void)in_sizes; (void)n_in; (void)ws_size; (void)out_size;
  const float* xf   = (const float*)d_in[0];
  // d_in[1] = x : unused by forward
  const float* yt   = (const float*)d_in[2];
  const float* pp   = (const float*)d_in[3];
  const float* eWih = (const float*)d_in[4];
  const float* eWhh = (const float*)d_in[5];
  const float* ebih = (const float*)d_in[6];
  const float* ebhh = (const float*)d_in[7];
  const float* dWih = (const float*)d_in[8];
  const float* dWhh = (const float*)d_in[9];
  const float* dbih = (const float*)d_in[10];
  const float* dbhh = (const float*)d_in[11];
  const float* thW0 = (const float*)d_in[12];
  const float* thb0 = (const float*)d_in[13];
  const float* thW1 = (const float*)d_in[14];
  const float* thb1 = (const float*)d_in[15];
  const float* clW0 = (const float*)d_in[16];
  const float* clb0 = (const float*)d_in[17];
  const float* clW1 = (const float*)d_in[18];
  const float* clb1 = (const float*)d_in[19];
  float* outp = (float*)d_out;
  u16* ws = (u16*)d_ws;  // needs W_TOTAL*2 ~= 1.04 MB of scratch

  cvt_weights<<<dim3((W_TOTAL + 255) / 256), dim3(256), 0, stream>>>(
      eWih, eWhh, dWih, dWhh, thW0, thW1, clW0, clW1, ws);
  encdec_kernel<<<dim3(128), dim3(512), 0, stream>>>(
      xf, yt, pp, ebih, ebhh, dbih, dbhh, thb0, thb1, clb0, clb1, ws, outp);
}